// Round 1
// baseline (757.928 us; speedup 1.0000x reference)
//
#include <hip/hip_runtime.h>
#include <cfloat>
#include <cstdint>

#define N_STM 65536
#define N_LTM 65536
#define TOPM 2048
#define NBINS 4096
#define CAND_CAP 4096
#define NSPLIT 64            // n-splits in gemm grid
#define KAPPA 0.05f
#define EPS_F 1e-8f
#define THRESH 0.5f

// ---------- helpers ----------
__device__ __forceinline__ unsigned int f2ord(float f) {
  unsigned int b = __float_as_uint(f);
  return b ^ ((b & 0x80000000u) ? 0xFFFFFFFFu : 0x80000000u);
}
__device__ __forceinline__ float ord2f(unsigned int u) {
  unsigned int b = (u & 0x80000000u) ? (u ^ 0x80000000u) : ~u;
  return __uint_as_float(b);
}

// ---------- top-k: histogram ----------
__global__ void k_hist(const float* __restrict__ h, const int* __restrict__ act,
                       int* __restrict__ hist) {
  int i = blockIdx.x * blockDim.x + threadIdx.x;
  if (i >= N_STM) return;
  if (act[i] > 0) {
    float v = h[i];
    int b = (int)(v * (float)NBINS);
    b = min(max(b, 0), NBINS - 1);
    atomicAdd(&hist[b], 1);
  }
}

// find smallest bin b with suffix-count >= TOPM
__global__ __launch_bounds__(1024) void k_thresh(const int* __restrict__ hist,
                                                 int* __restrict__ thrbin) {
  __shared__ int t[1024];
  int tid = threadIdx.x;
  int c0 = hist[tid * 4 + 0], c1 = hist[tid * 4 + 1];
  int c2 = hist[tid * 4 + 2], c3 = hist[tid * 4 + 3];
  int local = c0 + c1 + c2 + c3;
  t[tid] = local;
  __syncthreads();
  for (int off = 1; off < 1024; off <<= 1) {
    int v = (tid + off < 1024) ? t[tid + off] : 0;
    __syncthreads();
    t[tid] += v;
    __syncthreads();
  }
  int after = t[tid] - local;          // sum of chunks strictly after this one
  int s3 = c3, s2 = c2 + s3, s1 = c1 + s2, s0 = c0 + s1;
  int S0 = after + s0, S1 = after + s1, S2 = after + s2, S3 = after + s3, S4 = after;
  if (S0 >= TOPM && S1 < TOPM) *thrbin = tid * 4 + 0;
  if (S1 >= TOPM && S2 < TOPM) *thrbin = tid * 4 + 1;
  if (S2 >= TOPM && S3 < TOPM) *thrbin = tid * 4 + 2;
  if (S3 >= TOPM && S4 < TOPM) *thrbin = tid * 4 + 3;
}

__global__ void k_gather(const float* __restrict__ h, const int* __restrict__ act,
                         const int* __restrict__ thrbin,
                         unsigned long long* __restrict__ cand, int* __restrict__ cnt) {
  int i = blockIdx.x * blockDim.x + threadIdx.x;
  if (i >= N_STM) return;
  if (act[i] > 0) {
    float v = h[i];
    int b = (int)(v * (float)NBINS);
    b = min(max(b, 0), NBINS - 1);
    if (b >= *thrbin) {
      int pos = atomicAdd(cnt, 1);
      if (pos < CAND_CAP)
        cand[pos] = ((unsigned long long)f2ord(v) << 32) |
                    (unsigned long long)(0xFFFFFFFFu - (unsigned)i);
    }
  }
}

// one-block bitonic sort (descending) of candidate keys; emit sel+omega
__global__ __launch_bounds__(1024) void k_sortsel(const float* __restrict__ h,
                                                  const unsigned long long* __restrict__ cand,
                                                  const int* __restrict__ cnt,
                                                  int* __restrict__ sel,
                                                  float* __restrict__ omega) {
  __shared__ unsigned long long d[CAND_CAP];
  int tid = threadIdx.x;
  int n = *cnt; if (n > CAND_CAP) n = CAND_CAP;
  for (int i = tid; i < CAND_CAP; i += 1024) d[i] = (i < n) ? cand[i] : 0ull;
  __syncthreads();
  for (int k = 2; k <= CAND_CAP; k <<= 1) {
    for (int j = k >> 1; j > 0; j >>= 1) {
      for (int i = tid; i < CAND_CAP; i += 1024) {
        int ixj = i ^ j;
        if (ixj > i) {
          unsigned long long a = d[i], b = d[ixj];
          bool up = ((i & k) == 0);
          bool sw = up ? (a < b) : (a > b);   // descending sort
          if (sw) { d[i] = b; d[ixj] = a; }
        }
      }
      __syncthreads();
    }
  }
  for (int i = tid; i < TOPM; i += 1024) {
    unsigned int inv = (unsigned int)(d[i] & 0xFFFFFFFFull);
    int idx = (int)(0xFFFFFFFFu - inv);
    sel[i] = idx;
    omega[i] = KAPPA * h[idx];
  }
}

// ---------- normalize ltm_K rows (inactive -> zero row) ----------
__global__ void k_lknorm(const float* __restrict__ lk, const int* __restrict__ act,
                         float* __restrict__ lkn) {
  int tid = threadIdx.x;
  int row = blockIdx.x * 4 + (tid >> 6);
  int lane = tid & 63;
  float v = lk[row * 64 + lane];
  float ss = v * v;
  for (int off = 32; off; off >>= 1) ss += __shfl_xor(ss, off, 64);
  float denom = sqrtf(ss) + EPS_F;
  lkn[row * 64 + lane] = (act[row] > 0) ? (v / denom) : 0.0f;
}

// ---------- project selected stm_K -> K_proj and normalized kpn ----------
__global__ void k_proj(const float* __restrict__ stmK, const float* __restrict__ W,
                       const float* __restrict__ bp, const int* __restrict__ sel,
                       float* __restrict__ Kproj, float* __restrict__ kpn) {
  int m = blockIdx.x;
  int j = threadIdx.x;            // 64 threads
  int s = sel[m];
  float acc = bp[j];
#pragma unroll
  for (int k = 0; k < 16; ++k) acc += stmK[s * 16 + k] * W[k * 64 + j];
  float ss = acc * acc;
  for (int off = 32; off; off >>= 1) ss += __shfl_xor(ss, off, 64);
  float denom = sqrtf(ss) + EPS_F;
  Kproj[m * 64 + j] = acc;
  kpn[m * 64 + j] = acc / denom;
}

// ---------- fused fp32 GEMM + per-row argmax ----------
// grid (NSPLIT=64 n-splits, 16 m-tiles); block 256; tile 128m x 64n; thread 8m x 4n
__global__ __launch_bounds__(256) void k_gemm(const float* __restrict__ kpn,
                                              const float* __restrict__ lkn,
                                              unsigned long long* __restrict__ partials) {
  __shared__ float4 kpt[128][17];   // [m][k-chunk], padded stride
  __shared__ float4 lkt[64][17];    // [n][k-chunk]
  int tid = threadIdx.x;
  int tx = tid & 15, ty = tid >> 4;
  int mbase = blockIdx.y * 128;
  const float4* kp4 = (const float4*)kpn;
  const float4* lk4 = (const float4*)lkn;
  {
    int r = tid >> 4, c = tid & 15;
#pragma unroll
    for (int it = 0; it < 8; ++it)
      kpt[r + 16 * it][c] = kp4[(mbase + r + 16 * it) * 16 + c];
  }
  float bval[8]; int bidx[8];
#pragma unroll
  for (int i = 0; i < 8; ++i) { bval[i] = -FLT_MAX; bidx[i] = 0; }

  for (int t = 0; t < 16; ++t) {
    int nbase = blockIdx.x * 1024 + t * 64;
    __syncthreads();
    {
      int r = tid >> 4, c = tid & 15;
#pragma unroll
      for (int it = 0; it < 4; ++it)
        lkt[r + 16 * it][c] = lk4[(nbase + r + 16 * it) * 16 + c];
    }
    __syncthreads();
    float acc[8][4];
#pragma unroll
    for (int i = 0; i < 8; ++i)
#pragma unroll
      for (int j = 0; j < 4; ++j) acc[i][j] = 0.f;
#pragma unroll
    for (int k4 = 0; k4 < 16; ++k4) {
      float4 a[8], b[4];
#pragma unroll
      for (int i = 0; i < 8; ++i) a[i] = kpt[ty + 16 * i][k4];
#pragma unroll
      for (int j = 0; j < 4; ++j) b[j] = lkt[tx + 16 * j][k4];
#pragma unroll
      for (int i = 0; i < 8; ++i)
#pragma unroll
        for (int j = 0; j < 4; ++j)
          acc[i][j] += a[i].x * b[j].x + a[i].y * b[j].y + a[i].z * b[j].z + a[i].w * b[j].w;
    }
#pragma unroll
    for (int i = 0; i < 8; ++i)
#pragma unroll
      for (int j = 0; j < 4; ++j) {
        int n = nbase + tx + 16 * j;            // ascending n within thread
        if (acc[i][j] > bval[i]) { bval[i] = acc[i][j]; bidx[i] = n; }
      }
  }
  // block-level reduce over the 16 tx's sharing each m; reuse lkt as u64 buf
  __syncthreads();
  unsigned long long* red = (unsigned long long*)&lkt[0][0];  // 128*16*8 = 16KB
#pragma unroll
  for (int i = 0; i < 8; ++i)
    red[(ty + 16 * i) * 16 + tx] =
        ((unsigned long long)f2ord(bval[i]) << 32) |
        (unsigned long long)(0xFFFFFFFFu - (unsigned)bidx[i]);
  __syncthreads();
  if (tid < 128) {
    unsigned long long mx = red[tid * 16];
#pragma unroll
    for (int q = 1; q < 16; ++q) {
      unsigned long long v = red[tid * 16 + q];
      if (v > mx) mx = v;
    }
    partials[(mbase + tid) * NSPLIT + blockIdx.x] = mx;
  }
}

// ---------- reduce partials -> best idx + matched ----------
__global__ void k_redpart(const unsigned long long* __restrict__ partials,
                          int* __restrict__ best, int* __restrict__ matched) {
  int tid = threadIdx.x;
  int m = blockIdx.x * 4 + (tid >> 6);
  int lane = tid & 63;
  unsigned long long mx = partials[m * NSPLIT + lane];
  for (int off = 32; off; off >>= 1) {
    unsigned int lo = (unsigned int)(mx & 0xFFFFFFFFull);
    unsigned int hi = (unsigned int)(mx >> 32);
    lo = __shfl_xor(lo, off, 64);
    hi = __shfl_xor(hi, off, 64);
    unsigned long long o = ((unsigned long long)hi << 32) | lo;
    if (o > mx) mx = o;
  }
  if (lane == 0) {
    float v = ord2f((unsigned int)(mx >> 32));
    matched[m] = (v >= THRESH) ? 1 : 0;
    best[m] = (int)(0xFFFFFFFFu - (unsigned int)(mx & 0xFFFFFFFFull));
  }
}

// ---------- rank = exclusive prefix of unmatched over 2048 (one block) ----------
__global__ void k_rank(const int* __restrict__ matched, int* __restrict__ rank,
                       const float* __restrict__ fatigue, float* __restrict__ outF) {
  __shared__ int s[256];
  int tid = threadIdx.x;
  int base = tid * 8;
  int flags[8]; int c = 0;
#pragma unroll
  for (int q = 0; q < 8; ++q) { flags[q] = matched[base + q] ? 0 : 1; c += flags[q]; }
  s[tid] = c;
  __syncthreads();
  for (int off = 1; off < 256; off <<= 1) {
    int v = (tid >= off) ? s[tid - off] : 0;
    __syncthreads();
    s[tid] += v;
    __syncthreads();
  }
  int run = s[tid] - c;   // exclusive
#pragma unroll
  for (int q = 0; q < 8; ++q) {
    rank[base + q] = flags[q] ? run : -1;
    run += flags[q];
  }
  if (tid == 0) outF[0] = 0.2f * fatigue[0];
}

// ---------- inactive slot compaction ----------
__global__ void k_cnt(const int* __restrict__ act, int* __restrict__ counts) {
  int i = blockIdx.x * 256 + threadIdx.x;
  int v = (act[i] == 0) ? 1 : 0;
  unsigned long long ball = __ballot(v);
  if ((threadIdx.x & 63) == 0) atomicAdd(&counts[blockIdx.x], __popcll(ball));
}

__global__ void k_scan256(const int* __restrict__ in, int* __restrict__ out) {
  __shared__ int s[256];
  int tid = threadIdx.x;
  int x = in[tid];
  s[tid] = x;
  __syncthreads();
  for (int off = 1; off < 256; off <<= 1) {
    int v = (tid >= off) ? s[tid - off] : 0;
    __syncthreads();
    s[tid] += v;
    __syncthreads();
  }
  out[tid] = s[tid] - x;
}

__global__ void k_compact(const int* __restrict__ act, const int* __restrict__ offsets,
                          int* __restrict__ inact) {
  __shared__ int s[256];
  int tid = threadIdx.x;
  int i = blockIdx.x * 256 + tid;
  int v = (act[i] == 0) ? 1 : 0;
  s[tid] = v;
  __syncthreads();
  for (int off = 1; off < 256; off <<= 1) {
    int u = (tid >= off) ? s[tid - off] : 0;
    __syncthreads();
    s[tid] += u;
    __syncthreads();
  }
  if (v) inact[offsets[blockIdx.x] + s[tid] - v] = i;
}

// ---------- scatter writes into ltm outputs ----------
__global__ void k_scatter(const int* __restrict__ matched, const int* __restrict__ best,
                          const int* __restrict__ rank, const int* __restrict__ sel,
                          const float* __restrict__ omega, const float* __restrict__ Kproj,
                          const float* __restrict__ stmV, const float* __restrict__ stmE,
                          const int* __restrict__ inact,
                          float* __restrict__ outK, float* __restrict__ outV,
                          float* __restrict__ outE, float* __restrict__ outH) {
  int m = blockIdx.x;
  int t = threadIdx.x;   // 128
  int s = sel[m];
  float om = omega[m];
  if (matched[m]) {
    int b = best[m];
    if (t < 64) atomicAdd(&outK[b * 64 + t], om * Kproj[m * 64 + t]);
    atomicAdd(&outV[b * 128 + t], om * stmV[s * 128 + t]);
    if (t < 4) atomicAdd(&outE[b * 4 + t], om * stmE[s * 4 + t]);
    if (t == 0) atomicAdd(&outH[b], om);
  } else {
    int slot = inact[rank[m]];
    if (t < 64) outK[slot * 64 + t] = Kproj[m * 64 + t];
    outV[slot * 128 + t] = stmV[s * 128 + t];
    if (t < 4) outE[slot * 4 + t] = stmE[s * 4 + t];
    if (t == 0) outH[slot] = om;
  }
}

// ---------- stm_V row-norm clip ----------
__global__ void k_vnorm(const float* __restrict__ V, float* __restrict__ out) {
  int tid = threadIdx.x;
  int row = blockIdx.x * 4 + (tid >> 6);
  int lane = tid & 63;
  float a = V[row * 128 + lane];
  float b = V[row * 128 + 64 + lane];
  float ss = a * a + b * b;
  for (int off = 32; off; off >>= 1) ss += __shfl_xor(ss, off, 64);
  float scale = fminf(1.0f, 2.0f / (sqrtf(ss) + EPS_F));
  out[row * 128 + lane] = a * scale;
  out[row * 128 + 64 + lane] = b * scale;
}

// ---------- terrain blur (13-tap separable, zero pad) ----------
struct GW13 { float w[13]; };

__global__ void k_blurW(const float* __restrict__ in, float* __restrict__ out, GW13 g) {
  int idx = blockIdx.x * 256 + threadIdx.x;
  int w = idx % 96;
  float s = 0.f;
#pragma unroll
  for (int t = -6; t <= 6; ++t) {
    int ww = w + t;
    if (ww >= 0 && ww < 96) s += g.w[t + 6] * in[idx + t];
  }
  out[idx] = s;
}

__global__ void k_blurH(const float* __restrict__ in, float* __restrict__ out, GW13 g) {
  int idx = blockIdx.x * 256 + threadIdx.x;
  int h = (idx / 96) % 96;
  float s = 0.f;
#pragma unroll
  for (int t = -6; t <= 6; ++t) {
    int hh = h + t;
    if (hh >= 0 && hh < 96) s += g.w[t + 6] * in[idx + t * 96];
  }
  out[idx] = s;
}

__global__ void k_blurD(const float* __restrict__ in, const float* __restrict__ ltmT,
                        float* __restrict__ out, GW13 g) {
  int idx = blockIdx.x * 256 + threadIdx.x;
  int d = (idx / 9216) % 96;
  int c = idx / 884736;
  float s = 0.f;
#pragma unroll
  for (int t = -6; t <= 6; ++t) {
    int dd = d + t;
    if (dd >= 0 && dd < 96) s += g.w[t + 6] * in[idx + t * 9216];
  }
  float xi = (c == 0) ? 0.005f : 0.003f;
  out[idx] = ltmT[idx] + xi * s;
}

// ---------- launch ----------
extern "C" void kernel_launch(void* const* d_in, const int* in_sizes, int n_in,
                              void* d_out, int out_size, void* d_ws, size_t ws_size,
                              hipStream_t stream) {
  const float* stmK = (const float*)d_in[0];
  const float* stmV = (const float*)d_in[1];
  const float* stmE = (const float*)d_in[2];
  const float* stmH = (const float*)d_in[3];
  const float* ltmK = (const float*)d_in[4];
  const float* ltmV = (const float*)d_in[5];
  const float* ltmE = (const float*)d_in[6];
  const float* ltmH = (const float*)d_in[7];
  const float* Wp   = (const float*)d_in[8];
  const float* bp   = (const float*)d_in[9];
  const float* sT   = (const float*)d_in[10];
  const float* lT   = (const float*)d_in[11];
  const float* fat  = (const float*)d_in[12];
  const int*   sAct = (const int*)d_in[13];
  const int*   lAct = (const int*)d_in[14];

  float* out = (float*)d_out;
  float* outK  = out;
  float* outV  = out + 4194304;
  float* outE  = out + 12582912;
  float* outH  = out + 12845056;
  float* outSV = out + 12910592;
  float* outT  = out + 21299200;
  float* outF  = out + 25722880;

  // workspace carve (256B aligned)
  char* p = (char*)d_ws;
  auto alloc = [&](size_t bytes) -> void* {
    void* r = (void*)p;
    p += (bytes + 255) & ~(size_t)255;
    return r;
  };
  float* lkn      = (float*)alloc((size_t)N_LTM * 64 * 4);
  float* kpn      = (float*)alloc((size_t)TOPM * 64 * 4);
  float* Kproj    = (float*)alloc((size_t)TOPM * 64 * 4);
  unsigned long long* partials = (unsigned long long*)alloc((size_t)TOPM * NSPLIT * 8);
  int*   best     = (int*)alloc(TOPM * 4);
  int*   matched  = (int*)alloc(TOPM * 4);
  int*   rank     = (int*)alloc(TOPM * 4);
  int*   sel      = (int*)alloc(TOPM * 4);
  float* omega    = (float*)alloc(TOPM * 4);
  int*   hist     = (int*)alloc(NBINS * 4);
  int*   candcnt  = (int*)alloc(256);
  unsigned long long* cand = (unsigned long long*)alloc(CAND_CAP * 8);
  int*   thrbin   = (int*)alloc(256);
  int*   counts   = (int*)alloc(256 * 4);
  int*   offsets  = (int*)alloc(256 * 4);
  int*   inact    = (int*)alloc((size_t)N_LTM * 4);
  float* tmpA     = (float*)alloc((size_t)4423680 * 4);
  float* tmpB     = (float*)alloc((size_t)4423680 * 4);
  (void)ws_size; (void)in_sizes; (void)n_in; (void)out_size;

  // base copies of ltm arrays into outputs (overwritten/accumulated by scatter)
  hipMemcpyAsync(outK, ltmK, (size_t)4194304 * 4, hipMemcpyDeviceToDevice, stream);
  hipMemcpyAsync(outV, ltmV, (size_t)8388608 * 4, hipMemcpyDeviceToDevice, stream);
  hipMemcpyAsync(outE, ltmE, (size_t)262144 * 4, hipMemcpyDeviceToDevice, stream);
  hipMemcpyAsync(outH, ltmH, (size_t)65536 * 4, hipMemcpyDeviceToDevice, stream);

  hipMemsetAsync(hist, 0, NBINS * 4, stream);
  hipMemsetAsync(candcnt, 0, 256, stream);
  hipMemsetAsync(counts, 0, 256 * 4, stream);

  // top-M selection
  k_hist<<<256, 256, 0, stream>>>(stmH, sAct, hist);
  k_thresh<<<1, 1024, 0, stream>>>(hist, thrbin);
  k_gather<<<256, 256, 0, stream>>>(stmH, sAct, thrbin, cand, candcnt);
  k_sortsel<<<1, 1024, 0, stream>>>(stmH, cand, candcnt, sel, omega);

  // normalize + project
  k_lknorm<<<N_LTM / 4, 256, 0, stream>>>(ltmK, lAct, lkn);
  k_proj<<<TOPM, 64, 0, stream>>>(stmK, Wp, bp, sel, Kproj, kpn);

  // cosine-sim argmax (dominant)
  k_gemm<<<dim3(NSPLIT, 16), 256, 0, stream>>>(kpn, lkn, partials);
  k_redpart<<<TOPM / 4, 256, 0, stream>>>(partials, best, matched);

  // ranks + inactive slot list
  k_rank<<<1, 256, 0, stream>>>(matched, rank, fat, outF);
  k_cnt<<<256, 256, 0, stream>>>(lAct, counts);
  k_scan256<<<1, 256, 0, stream>>>(counts, offsets);
  k_compact<<<256, 256, 0, stream>>>(lAct, offsets, inact);

  // scatter into ltm outputs
  k_scatter<<<TOPM, 128, 0, stream>>>(matched, best, rank, sel, omega, Kproj,
                                      stmV, stmE, inact, outK, outV, outE, outH);

  // stm_V normalization
  k_vnorm<<<N_STM / 4, 256, 0, stream>>>(stmV, outSV);

  // terrain blur
  GW13 g;
  {
    float s = 0.f;
    for (int i = -6; i <= 6; ++i) {
      float v = expf(-0.5f * ((float)i / 2.0f) * ((float)i / 2.0f));
      g.w[i + 6] = v;
      s += v;
    }
    for (int i = 0; i < 13; ++i) g.w[i] /= s;
  }
  int tblocks = 4423680 / 256;
  k_blurW<<<tblocks, 256, 0, stream>>>(sT, tmpA, g);
  k_blurH<<<tblocks, 256, 0, stream>>>(tmpA, tmpB, g);
  k_blurD<<<tblocks, 256, 0, stream>>>(tmpB, lT, outT, g);
}

// Round 2
// 740.485 us; speedup vs baseline: 1.0236x; 1.0236x over previous
//
#include <hip/hip_runtime.h>
#include <hip/hip_bf16.h>
#include <cfloat>
#include <cstdint>

#define N_STM 65536
#define N_LTM 65536
#define TOPM 2048
#define NBINS 4096
#define CAND_CAP 4096
#define KAPPA 0.05f
#define EPS_F 1e-8f
#define THRESH 0.5f
#define MARGIN 0.01f

typedef __attribute__((ext_vector_type(8))) __bf16 bf16x8;
typedef __attribute__((ext_vector_type(4))) float f32x4;

// ---------- helpers ----------
__device__ __forceinline__ unsigned int f2ord(float f) {
  unsigned int b = __float_as_uint(f);
  return b ^ ((b & 0x80000000u) ? 0xFFFFFFFFu : 0x80000000u);
}
__device__ __forceinline__ float ord2f(unsigned int u) {
  unsigned int b = (u & 0x80000000u) ? (u ^ 0x80000000u) : ~u;
  return __uint_as_float(b);
}
__device__ __forceinline__ unsigned short f2bf(float f) {
  __hip_bfloat16 h = __float2bfloat16(f);
  return __builtin_bit_cast(unsigned short, h);
}
__device__ __forceinline__ unsigned long long shflxor64(unsigned long long v, int mask) {
  unsigned int lo = (unsigned int)v, hi = (unsigned int)(v >> 32);
  lo = __shfl_xor(lo, mask, 64);
  hi = __shfl_xor(hi, mask, 64);
  return ((unsigned long long)hi << 32) | lo;
}

// ---------- top-k: histogram ----------
__global__ void k_hist(const float* __restrict__ h, const int* __restrict__ act,
                       int* __restrict__ hist) {
  int i = blockIdx.x * blockDim.x + threadIdx.x;
  if (i >= N_STM) return;
  if (act[i] > 0) {
    float v = h[i];
    int b = (int)(v * (float)NBINS);
    b = min(max(b, 0), NBINS - 1);
    atomicAdd(&hist[b], 1);
  }
}

__global__ __launch_bounds__(1024) void k_thresh(const int* __restrict__ hist,
                                                 int* __restrict__ thrbin) {
  __shared__ int t[1024];
  int tid = threadIdx.x;
  int c0 = hist[tid * 4 + 0], c1 = hist[tid * 4 + 1];
  int c2 = hist[tid * 4 + 2], c3 = hist[tid * 4 + 3];
  int local = c0 + c1 + c2 + c3;
  t[tid] = local;
  __syncthreads();
  for (int off = 1; off < 1024; off <<= 1) {
    int v = (tid + off < 1024) ? t[tid + off] : 0;
    __syncthreads();
    t[tid] += v;
    __syncthreads();
  }
  int after = t[tid] - local;
  int s3 = c3, s2 = c2 + s3, s1 = c1 + s2, s0 = c0 + s1;
  int S0 = after + s0, S1 = after + s1, S2 = after + s2, S3 = after + s3, S4 = after;
  if (S0 >= TOPM && S1 < TOPM) *thrbin = tid * 4 + 0;
  if (S1 >= TOPM && S2 < TOPM) *thrbin = tid * 4 + 1;
  if (S2 >= TOPM && S3 < TOPM) *thrbin = tid * 4 + 2;
  if (S3 >= TOPM && S4 < TOPM) *thrbin = tid * 4 + 3;
}

__global__ void k_gather(const float* __restrict__ h, const int* __restrict__ act,
                         const int* __restrict__ thrbin,
                         unsigned long long* __restrict__ cand, int* __restrict__ cnt) {
  int i = blockIdx.x * blockDim.x + threadIdx.x;
  if (i >= N_STM) return;
  if (act[i] > 0) {
    float v = h[i];
    int b = (int)(v * (float)NBINS);
    b = min(max(b, 0), NBINS - 1);
    if (b >= *thrbin) {
      int pos = atomicAdd(cnt, 1);
      if (pos < CAND_CAP)
        cand[pos] = ((unsigned long long)f2ord(v) << 32) |
                    (unsigned long long)(0xFFFFFFFFu - (unsigned)i);
    }
  }
}

__global__ __launch_bounds__(1024) void k_sortsel(const float* __restrict__ h,
                                                  const unsigned long long* __restrict__ cand,
                                                  const int* __restrict__ cnt,
                                                  int* __restrict__ sel,
                                                  float* __restrict__ omega) {
  __shared__ unsigned long long d[CAND_CAP];
  int tid = threadIdx.x;
  int n = *cnt; if (n > CAND_CAP) n = CAND_CAP;
  for (int i = tid; i < CAND_CAP; i += 1024) d[i] = (i < n) ? cand[i] : 0ull;
  __syncthreads();
  for (int k = 2; k <= CAND_CAP; k <<= 1) {
    for (int j = k >> 1; j > 0; j >>= 1) {
      for (int i = tid; i < CAND_CAP; i += 1024) {
        int ixj = i ^ j;
        if (ixj > i) {
          unsigned long long a = d[i], b = d[ixj];
          bool up = ((i & k) == 0);
          bool sw = up ? (a < b) : (a > b);
          if (sw) { d[i] = b; d[ixj] = a; }
        }
      }
      __syncthreads();
    }
  }
  for (int i = tid; i < TOPM; i += 1024) {
    unsigned int inv = (unsigned int)(d[i] & 0xFFFFFFFFull);
    int idx = (int)(0xFFFFFFFFu - inv);
    sel[i] = idx;
    omega[i] = KAPPA * h[idx];
  }
}

// ---------- normalize ltm_K rows (inactive -> zero); fp32 + bf16 ----------
__global__ void k_lknorm(const float* __restrict__ lk, const int* __restrict__ act,
                         float* __restrict__ lkn, unsigned short* __restrict__ lknb) {
  int tid = threadIdx.x;
  int row = blockIdx.x * 4 + (tid >> 6);
  int lane = tid & 63;
  float v = lk[row * 64 + lane];
  float ss = v * v;
  for (int off = 32; off; off >>= 1) ss += __shfl_xor(ss, off, 64);
  float denom = sqrtf(ss) + EPS_F;
  float r = (act[row] > 0) ? (v / denom) : 0.0f;
  lkn[row * 64 + lane] = r;
  lknb[row * 64 + lane] = f2bf(r);
}

// ---------- project selected stm_K; fp32 Kproj + fp32/bf16 normalized ----------
__global__ void k_proj(const float* __restrict__ stmK, const float* __restrict__ W,
                       const float* __restrict__ bp, const int* __restrict__ sel,
                       float* __restrict__ Kproj, float* __restrict__ kpn,
                       unsigned short* __restrict__ kpnb) {
  int m = blockIdx.x;
  int j = threadIdx.x;            // 64 threads
  int s = sel[m];
  float acc = bp[j];
#pragma unroll
  for (int k = 0; k < 16; ++k) acc += stmK[s * 16 + k] * W[k * 64 + j];
  float ss = acc * acc;
  for (int off = 32; off; off >>= 1) ss += __shfl_xor(ss, off, 64);
  float denom = sqrtf(ss) + EPS_F;
  float r = acc / denom;
  Kproj[m * 64 + j] = acc;
  kpn[m * 64 + j] = r;
  kpnb[m * 64 + j] = f2bf(r);
}

// ---------- sweep 1: bf16 MFMA sims, per-(m, 256n-split) max key ----------
// grid (256 n-splits, 32 m-blocks of 64), block 256 = 4 waves; wave: 16m x 256n
__global__ __launch_bounds__(256) void k_simmax(const unsigned short* __restrict__ kpnb,
                                                const unsigned short* __restrict__ lknb,
                                                unsigned long long* __restrict__ partials) {
  int tid = threadIdx.x;
  int lane = tid & 63, wv = tid >> 6;
  int mwave = blockIdx.y * 64 + wv * 16;
  int nbase = blockIdx.x * 256;
  int lg = lane >> 4, lc = lane & 15;
  const bf16x8* pa = reinterpret_cast<const bf16x8*>(kpnb + (size_t)(mwave + lc) * 64 + lg * 8);
  bf16x8 a0 = pa[0];
  bf16x8 a1 = pa[4];               // +32 bf16
  const unsigned short* lrow = lknb + (size_t)(nbase + lc) * 64 + lg * 8;
  f32x4 acc[16];
#pragma unroll
  for (int t = 0; t < 16; ++t) {
    const bf16x8* pb = reinterpret_cast<const bf16x8*>(lrow + (size_t)t * 16 * 64);
    f32x4 z = {0.f, 0.f, 0.f, 0.f};
    f32x4 c = __builtin_amdgcn_mfma_f32_16x16x32_bf16(a0, pb[0], z, 0, 0, 0);
    acc[t] = __builtin_amdgcn_mfma_f32_16x16x32_bf16(a1, pb[4], c, 0, 0, 0);
  }
#pragma unroll
  for (int r = 0; r < 4; ++r) {
    float bv = acc[0][r]; int bt = 0;
#pragma unroll
    for (int t = 1; t < 16; ++t)
      if (acc[t][r] > bv) { bv = acc[t][r]; bt = t; }   // ascending n: ties -> lowest n
    int bn = nbase + bt * 16 + lc;
    unsigned long long key = ((unsigned long long)f2ord(bv) << 32) |
                             (unsigned long long)(0xFFFFFFFFu - (unsigned)bn);
#pragma unroll
    for (int mk = 1; mk <= 8; mk <<= 1) {
      unsigned long long o = shflxor64(key, mk);
      if (o > key) key = o;
    }
    if (lc == 0)
      partials[(size_t)(mwave + lg * 4 + r) * 256 + blockIdx.x] = key;
  }
}

// ---------- reduce 256 split-maxes -> per-row threshold ----------
__global__ __launch_bounds__(256) void k_redmax(const unsigned long long* __restrict__ partials,
                                                float* __restrict__ thr) {
  int m = blockIdx.x;
  int tid = threadIdx.x;
  unsigned long long key = partials[(size_t)m * 256 + tid];
  for (int mk = 1; mk < 64; mk <<= 1) {
    unsigned long long o = shflxor64(key, mk);
    if (o > key) key = o;
  }
  __shared__ unsigned long long s[4];
  if ((tid & 63) == 0) s[tid >> 6] = key;
  __syncthreads();
  if (tid == 0) {
    unsigned long long k0 = s[0];
    for (int i = 1; i < 4; ++i) if (s[i] > k0) k0 = s[i];
    thr[m] = ord2f((unsigned int)(k0 >> 32)) - MARGIN;
  }
}

// ---------- sweep 2: recompute sims; candidates get exact fp32 dot ----------
__global__ __launch_bounds__(256) void k_rescue(const unsigned short* __restrict__ kpnb,
                                                const unsigned short* __restrict__ lknb,
                                                const float* __restrict__ thr,
                                                const float* __restrict__ kpn,
                                                const float* __restrict__ lkn,
                                                unsigned long long* __restrict__ finalkey) {
  int tid = threadIdx.x;
  int lane = tid & 63, wv = tid >> 6;
  int mwave = blockIdx.y * 64 + wv * 16;
  int nbase = blockIdx.x * 256;
  int lg = lane >> 4, lc = lane & 15;
  const bf16x8* pa = reinterpret_cast<const bf16x8*>(kpnb + (size_t)(mwave + lc) * 64 + lg * 8);
  bf16x8 a0 = pa[0];
  bf16x8 a1 = pa[4];
  const unsigned short* lrow = lknb + (size_t)(nbase + lc) * 64 + lg * 8;
  f32x4 acc[16];
#pragma unroll
  for (int t = 0; t < 16; ++t) {
    const bf16x8* pb = reinterpret_cast<const bf16x8*>(lrow + (size_t)t * 16 * 64);
    f32x4 z = {0.f, 0.f, 0.f, 0.f};
    f32x4 c = __builtin_amdgcn_mfma_f32_16x16x32_bf16(a0, pb[0], z, 0, 0, 0);
    acc[t] = __builtin_amdgcn_mfma_f32_16x16x32_bf16(a1, pb[4], c, 0, 0, 0);
  }
  float tv[4];
#pragma unroll
  for (int r = 0; r < 4; ++r) tv[r] = thr[mwave + lg * 4 + r];
#pragma unroll
  for (int t = 0; t < 16; ++t) {
#pragma unroll
    for (int r = 0; r < 4; ++r) {
      if (acc[t][r] >= tv[r]) {                       // rare (~1.4 per row globally)
        int n = nbase + t * 16 + lc;
        int m = mwave + lg * 4 + r;
        const float* ka = kpn + (size_t)m * 64;
        const float* kb = lkn + (size_t)n * 64;
        float ex = 0.f;
        for (int k = 0; k < 64; ++k) ex += ka[k] * kb[k];
        unsigned long long key = ((unsigned long long)f2ord(ex) << 32) |
                                 (unsigned long long)(0xFFFFFFFFu - (unsigned)n);
        atomicMax(finalkey + m, key);
      }
    }
  }
}

__global__ void k_finalize(const unsigned long long* __restrict__ finalkey,
                           int* __restrict__ best, int* __restrict__ matched) {
  int m = blockIdx.x * 256 + threadIdx.x;
  unsigned long long k = finalkey[m];
  float v = ord2f((unsigned int)(k >> 32));
  matched[m] = (v >= THRESH) ? 1 : 0;
  best[m] = (int)(0xFFFFFFFFu - (unsigned int)(k & 0xFFFFFFFFull));
}

// ---------- rank = exclusive prefix of unmatched (one block) ----------
__global__ void k_rank(const int* __restrict__ matched, int* __restrict__ rank,
                       const float* __restrict__ fatigue, float* __restrict__ outF) {
  __shared__ int s[256];
  int tid = threadIdx.x;
  int base = tid * 8;
  int flags[8]; int c = 0;
#pragma unroll
  for (int q = 0; q < 8; ++q) { flags[q] = matched[base + q] ? 0 : 1; c += flags[q]; }
  s[tid] = c;
  __syncthreads();
  for (int off = 1; off < 256; off <<= 1) {
    int v = (tid >= off) ? s[tid - off] : 0;
    __syncthreads();
    s[tid] += v;
    __syncthreads();
  }
  int run = s[tid] - c;
#pragma unroll
  for (int q = 0; q < 8; ++q) {
    rank[base + q] = flags[q] ? run : -1;
    run += flags[q];
  }
  if (tid == 0) outF[0] = 0.2f * fatigue[0];
}

// ---------- inactive slot compaction ----------
__global__ void k_cnt(const int* __restrict__ act, int* __restrict__ counts) {
  int i = blockIdx.x * 256 + threadIdx.x;
  int v = (act[i] == 0) ? 1 : 0;
  unsigned long long ball = __ballot(v);
  if ((threadIdx.x & 63) == 0) atomicAdd(&counts[blockIdx.x], __popcll(ball));
}

__global__ void k_scan256(const int* __restrict__ in, int* __restrict__ out) {
  __shared__ int s[256];
  int tid = threadIdx.x;
  int x = in[tid];
  s[tid] = x;
  __syncthreads();
  for (int off = 1; off < 256; off <<= 1) {
    int v = (tid >= off) ? s[tid - off] : 0;
    __syncthreads();
    s[tid] += v;
    __syncthreads();
  }
  out[tid] = s[tid] - x;
}

__global__ void k_compact(const int* __restrict__ act, const int* __restrict__ offsets,
                          int* __restrict__ inact) {
  __shared__ int s[256];
  int tid = threadIdx.x;
  int i = blockIdx.x * 256 + tid;
  int v = (act[i] == 0) ? 1 : 0;
  s[tid] = v;
  __syncthreads();
  for (int off = 1; off < 256; off <<= 1) {
    int u = (tid >= off) ? s[tid - off] : 0;
    __syncthreads();
    s[tid] += u;
    __syncthreads();
  }
  if (v) inact[offsets[blockIdx.x] + s[tid] - v] = i;
}

// ---------- scatter writes into ltm outputs ----------
__global__ void k_scatter(const int* __restrict__ matched, const int* __restrict__ best,
                          const int* __restrict__ rank, const int* __restrict__ sel,
                          const float* __restrict__ omega, const float* __restrict__ Kproj,
                          const float* __restrict__ stmV, const float* __restrict__ stmE,
                          const int* __restrict__ inact,
                          float* __restrict__ outK, float* __restrict__ outV,
                          float* __restrict__ outE, float* __restrict__ outH) {
  int m = blockIdx.x;
  int t = threadIdx.x;   // 128
  int s = sel[m];
  float om = omega[m];
  if (matched[m]) {
    int b = best[m];
    if (t < 64) atomicAdd(&outK[b * 64 + t], om * Kproj[m * 64 + t]);
    atomicAdd(&outV[b * 128 + t], om * stmV[s * 128 + t]);
    if (t < 4) atomicAdd(&outE[b * 4 + t], om * stmE[s * 4 + t]);
    if (t == 0) atomicAdd(&outH[b], om);
  } else {
    int slot = inact[rank[m]];
    if (t < 64) outK[slot * 64 + t] = Kproj[m * 64 + t];
    outV[slot * 128 + t] = stmV[s * 128 + t];
    if (t < 4) outE[slot * 4 + t] = stmE[s * 4 + t];
    if (t == 0) outH[slot] = om;
  }
}

// ---------- stm_V row-norm clip ----------
__global__ void k_vnorm(const float* __restrict__ V, float* __restrict__ out) {
  int tid = threadIdx.x;
  int row = blockIdx.x * 4 + (tid >> 6);
  int lane = tid & 63;
  float a = V[row * 128 + lane];
  float b = V[row * 128 + 64 + lane];
  float ss = a * a + b * b;
  for (int off = 32; off; off >>= 1) ss += __shfl_xor(ss, off, 64);
  float scale = fminf(1.0f, 2.0f / (sqrtf(ss) + EPS_F));
  out[row * 128 + lane] = a * scale;
  out[row * 128 + 64 + lane] = b * scale;
}

// ---------- terrain blur (13-tap separable, zero pad) ----------
struct GW13 { float w[13]; };

__global__ void k_blurW(const float* __restrict__ in, float* __restrict__ out, GW13 g) {
  int idx = blockIdx.x * 256 + threadIdx.x;
  int w = idx % 96;
  float s = 0.f;
#pragma unroll
  for (int t = -6; t <= 6; ++t) {
    int ww = w + t;
    if (ww >= 0 && ww < 96) s += g.w[t + 6] * in[idx + t];
  }
  out[idx] = s;
}

__global__ void k_blurH(const float* __restrict__ in, float* __restrict__ out, GW13 g) {
  int idx = blockIdx.x * 256 + threadIdx.x;
  int h = (idx / 96) % 96;
  float s = 0.f;
#pragma unroll
  for (int t = -6; t <= 6; ++t) {
    int hh = h + t;
    if (hh >= 0 && hh < 96) s += g.w[t + 6] * in[idx + t * 96];
  }
  out[idx] = s;
}

__global__ void k_blurD(const float* __restrict__ in, const float* __restrict__ ltmT,
                        float* __restrict__ out, GW13 g) {
  int idx = blockIdx.x * 256 + threadIdx.x;
  int d = (idx / 9216) % 96;
  int c = idx / 884736;
  float s = 0.f;
#pragma unroll
  for (int t = -6; t <= 6; ++t) {
    int dd = d + t;
    if (dd >= 0 && dd < 96) s += g.w[t + 6] * in[idx + t * 9216];
  }
  float xi = (c == 0) ? 0.005f : 0.003f;
  out[idx] = ltmT[idx] + xi * s;
}

// ---------- launch ----------
extern "C" void kernel_launch(void* const* d_in, const int* in_sizes, int n_in,
                              void* d_out, int out_size, void* d_ws, size_t ws_size,
                              hipStream_t stream) {
  const float* stmK = (const float*)d_in[0];
  const float* stmV = (const float*)d_in[1];
  const float* stmE = (const float*)d_in[2];
  const float* stmH = (const float*)d_in[3];
  const float* ltmK = (const float*)d_in[4];
  const float* ltmV = (const float*)d_in[5];
  const float* ltmE = (const float*)d_in[6];
  const float* ltmH = (const float*)d_in[7];
  const float* Wp   = (const float*)d_in[8];
  const float* bp   = (const float*)d_in[9];
  const float* sT   = (const float*)d_in[10];
  const float* lT   = (const float*)d_in[11];
  const float* fat  = (const float*)d_in[12];
  const int*   sAct = (const int*)d_in[13];
  const int*   lAct = (const int*)d_in[14];

  float* out = (float*)d_out;
  float* outK  = out;
  float* outV  = out + 4194304;
  float* outE  = out + 12582912;
  float* outH  = out + 12845056;
  float* outSV = out + 12910592;
  float* outT  = out + 21299200;
  float* outF  = out + 25722880;

  char* p = (char*)d_ws;
  auto alloc = [&](size_t bytes) -> void* {
    void* r = (void*)p;
    p += (bytes + 255) & ~(size_t)255;
    return r;
  };
  float* lkn      = (float*)alloc((size_t)N_LTM * 64 * 4);
  unsigned short* lknb = (unsigned short*)alloc((size_t)N_LTM * 64 * 2);
  float* kpn      = (float*)alloc((size_t)TOPM * 64 * 4);
  unsigned short* kpnb = (unsigned short*)alloc((size_t)TOPM * 64 * 2);
  float* Kproj    = (float*)alloc((size_t)TOPM * 64 * 4);
  float* thr      = (float*)alloc(TOPM * 4);
  unsigned long long* finalkey = (unsigned long long*)alloc(TOPM * 8);
  int*   best     = (int*)alloc(TOPM * 4);
  int*   matched  = (int*)alloc(TOPM * 4);
  int*   rank     = (int*)alloc(TOPM * 4);
  int*   sel      = (int*)alloc(TOPM * 4);
  float* omega    = (float*)alloc(TOPM * 4);
  int*   hist     = (int*)alloc(NBINS * 4);
  int*   candcnt  = (int*)alloc(256);
  unsigned long long* cand = (unsigned long long*)alloc(CAND_CAP * 8);
  int*   thrbin   = (int*)alloc(256);
  int*   counts   = (int*)alloc(256 * 4);
  int*   offsets  = (int*)alloc(256 * 4);
  int*   inact    = (int*)alloc((size_t)N_LTM * 4);
  float* tmpA     = (float*)alloc((size_t)4423680 * 4);
  float* tmpB     = (float*)alloc((size_t)4423680 * 4);
  // partials (2048*256*8B = 4MB) aliased onto tmpA: written by k_simmax, read by
  // k_redmax, both strictly before k_blurW writes tmpA (same stream = ordered).
  unsigned long long* partials = (unsigned long long*)tmpA;
  (void)ws_size; (void)in_sizes; (void)n_in; (void)out_size;

  hipMemcpyAsync(outK, ltmK, (size_t)4194304 * 4, hipMemcpyDeviceToDevice, stream);
  hipMemcpyAsync(outV, ltmV, (size_t)8388608 * 4, hipMemcpyDeviceToDevice, stream);
  hipMemcpyAsync(outE, ltmE, (size_t)262144 * 4, hipMemcpyDeviceToDevice, stream);
  hipMemcpyAsync(outH, ltmH, (size_t)65536 * 4, hipMemcpyDeviceToDevice, stream);

  hipMemsetAsync(hist, 0, NBINS * 4, stream);
  hipMemsetAsync(candcnt, 0, 256, stream);
  hipMemsetAsync(counts, 0, 256 * 4, stream);
  hipMemsetAsync(finalkey, 0, TOPM * 8, stream);

  // top-M selection
  k_hist<<<256, 256, 0, stream>>>(stmH, sAct, hist);
  k_thresh<<<1, 1024, 0, stream>>>(hist, thrbin);
  k_gather<<<256, 256, 0, stream>>>(stmH, sAct, thrbin, cand, candcnt);
  k_sortsel<<<1, 1024, 0, stream>>>(stmH, cand, candcnt, sel, omega);

  // normalize + project (fp32 + bf16 copies)
  k_lknorm<<<N_LTM / 4, 256, 0, stream>>>(ltmK, lAct, lkn, lknb);
  k_proj<<<TOPM, 64, 0, stream>>>(stmK, Wp, bp, sel, Kproj, kpn, kpnb);

  // MFMA sims: sweep1 max -> threshold -> sweep2 exact rescue
  k_simmax<<<dim3(256, 32), 256, 0, stream>>>(kpnb, lknb, partials);
  k_redmax<<<TOPM, 256, 0, stream>>>(partials, thr);
  k_rescue<<<dim3(256, 32), 256, 0, stream>>>(kpnb, lknb, thr, kpn, lkn, finalkey);
  k_finalize<<<TOPM / 256, 256, 0, stream>>>(finalkey, best, matched);

  // ranks + inactive slot list
  k_rank<<<1, 256, 0, stream>>>(matched, rank, fat, outF);
  k_cnt<<<256, 256, 0, stream>>>(lAct, counts);
  k_scan256<<<1, 256, 0, stream>>>(counts, offsets);
  k_compact<<<256, 256, 0, stream>>>(lAct, offsets, inact);

  // scatter into ltm outputs
  k_scatter<<<TOPM, 128, 0, stream>>>(matched, best, rank, sel, omega, Kproj,
                                      stmV, stmE, inact, outK, outV, outE, outH);

  // stm_V normalization
  k_vnorm<<<N_STM / 4, 256, 0, stream>>>(stmV, outSV);

  // terrain blur
  GW13 g;
  {
    float s = 0.f;
    for (int i = -6; i <= 6; ++i) {
      float v = expf(-0.5f * ((float)i / 2.0f) * ((float)i / 2.0f));
      g.w[i + 6] = v;
      s += v;
    }
    for (int i = 0; i < 13; ++i) g.w[i] /= s;
  }
  int tblocks = 4423680 / 256;
  k_blurW<<<tblocks, 256, 0, stream>>>(sT, tmpA, g);
  k_blurH<<<tblocks, 256, 0, stream>>>(tmpA, tmpB, g);
  k_blurD<<<tblocks, 256, 0, stream>>>(tmpB, lT, outT, g);
}

// Round 3
// 542.538 us; speedup vs baseline: 1.3970x; 1.3649x over previous
//
#include <hip/hip_runtime.h>
#include <hip/hip_bf16.h>
#include <cfloat>
#include <cstdint>

#define N_STM 65536
#define N_LTM 65536
#define TOPM 2048
#define NBINS 4096
#define CAND_CAP 4096
#define NSPL 512          // 128-col splits of N_LTM
#define WCAP 8192         // worklist capacity (expected ~3K entries)
#define KAPPA 0.05f
#define EPS_F 1e-8f
#define THRESH 0.5f
#define MARGIN 0.01f      // > 2 * bf16 sim error (7.8e-3)

typedef __attribute__((ext_vector_type(8))) __bf16 bf16x8;
typedef __attribute__((ext_vector_type(4))) float f32x4;

// ---------- helpers ----------
__device__ __forceinline__ unsigned int f2ord(float f) {
  unsigned int b = __float_as_uint(f);
  return b ^ ((b & 0x80000000u) ? 0xFFFFFFFFu : 0x80000000u);
}
__device__ __forceinline__ float ord2f(unsigned int u) {
  unsigned int b = (u & 0x80000000u) ? (u ^ 0x80000000u) : ~u;
  return __uint_as_float(b);
}
__device__ __forceinline__ unsigned short f2bf(float f) {
  __hip_bfloat16 h = __float2bfloat16(f);
  return __builtin_bit_cast(unsigned short, h);
}
__device__ __forceinline__ unsigned long long shflxor64(unsigned long long v, int mask) {
  unsigned int lo = (unsigned int)v, hi = (unsigned int)(v >> 32);
  lo = __shfl_xor(lo, mask, 64);
  hi = __shfl_xor(hi, mask, 64);
  return ((unsigned long long)hi << 32) | lo;
}

// ---------- one-shot zero init (replaces 4 memsets) ----------
__global__ void k_zero(int* __restrict__ hist, int* __restrict__ counts,
                       int* __restrict__ candcnt, int* __restrict__ wcnt,
                       unsigned long long* __restrict__ finalkey) {
  int i = blockIdx.x * 256 + threadIdx.x;   // grid 16 -> 4096 threads
  hist[i] = 0;
  if (i < 2048) finalkey[i] = 0ull;
  if (i < 256) counts[i] = 0;
  if (i == 0) { candcnt[0] = 0; wcnt[0] = 0; }
}

// ---------- top-k: histogram ----------
__global__ void k_hist(const float* __restrict__ h, const int* __restrict__ act,
                       int* __restrict__ hist) {
  int i = blockIdx.x * blockDim.x + threadIdx.x;
  if (i >= N_STM) return;
  if (act[i] > 0) {
    float v = h[i];
    int b = (int)(v * (float)NBINS);
    b = min(max(b, 0), NBINS - 1);
    atomicAdd(&hist[b], 1);
  }
}

__global__ __launch_bounds__(1024) void k_thresh(const int* __restrict__ hist,
                                                 int* __restrict__ thrbin) {
  __shared__ int t[1024];
  int tid = threadIdx.x;
  int c0 = hist[tid * 4 + 0], c1 = hist[tid * 4 + 1];
  int c2 = hist[tid * 4 + 2], c3 = hist[tid * 4 + 3];
  int local = c0 + c1 + c2 + c3;
  t[tid] = local;
  __syncthreads();
  for (int off = 1; off < 1024; off <<= 1) {
    int v = (tid + off < 1024) ? t[tid + off] : 0;
    __syncthreads();
    t[tid] += v;
    __syncthreads();
  }
  int after = t[tid] - local;
  int s3 = c3, s2 = c2 + s3, s1 = c1 + s2, s0 = c0 + s1;
  int S0 = after + s0, S1 = after + s1, S2 = after + s2, S3 = after + s3, S4 = after;
  if (S0 >= TOPM && S1 < TOPM) *thrbin = tid * 4 + 0;
  if (S1 >= TOPM && S2 < TOPM) *thrbin = tid * 4 + 1;
  if (S2 >= TOPM && S3 < TOPM) *thrbin = tid * 4 + 2;
  if (S3 >= TOPM && S4 < TOPM) *thrbin = tid * 4 + 3;
}

__global__ void k_gather(const float* __restrict__ h, const int* __restrict__ act,
                         const int* __restrict__ thrbin,
                         unsigned long long* __restrict__ cand, int* __restrict__ cnt) {
  int i = blockIdx.x * blockDim.x + threadIdx.x;
  if (i >= N_STM) return;
  if (act[i] > 0) {
    float v = h[i];
    int b = (int)(v * (float)NBINS);
    b = min(max(b, 0), NBINS - 1);
    if (b >= *thrbin) {
      int pos = atomicAdd(cnt, 1);
      if (pos < CAND_CAP)
        cand[pos] = ((unsigned long long)f2ord(v) << 32) |
                    (unsigned long long)(0xFFFFFFFFu - (unsigned)i);
    }
  }
}

__global__ __launch_bounds__(1024) void k_sortsel(const float* __restrict__ h,
                                                  const unsigned long long* __restrict__ cand,
                                                  const int* __restrict__ cnt,
                                                  int* __restrict__ sel,
                                                  float* __restrict__ omega) {
  __shared__ unsigned long long d[CAND_CAP];
  int tid = threadIdx.x;
  int n = *cnt; if (n > CAND_CAP) n = CAND_CAP;
  for (int i = tid; i < CAND_CAP; i += 1024) d[i] = (i < n) ? cand[i] : 0ull;
  __syncthreads();
  for (int k = 2; k <= CAND_CAP; k <<= 1) {
    for (int j = k >> 1; j > 0; j >>= 1) {
      for (int i = tid; i < CAND_CAP; i += 1024) {
        int ixj = i ^ j;
        if (ixj > i) {
          unsigned long long a = d[i], b = d[ixj];
          bool up = ((i & k) == 0);
          bool sw = up ? (a < b) : (a > b);
          if (sw) { d[i] = b; d[ixj] = a; }
        }
      }
      __syncthreads();
    }
  }
  for (int i = tid; i < TOPM; i += 1024) {
    unsigned int inv = (unsigned int)(d[i] & 0xFFFFFFFFull);
    int idx = (int)(0xFFFFFFFFu - inv);
    sel[i] = idx;
    omega[i] = KAPPA * h[idx];
  }
}

// ---------- normalize ltm_K rows (inactive -> zero); fp32 + bf16 ----------
__global__ void k_lknorm(const float* __restrict__ lk, const int* __restrict__ act,
                         float* __restrict__ lkn, unsigned short* __restrict__ lknb) {
  int tid = threadIdx.x;
  int row = blockIdx.x * 4 + (tid >> 6);
  int lane = tid & 63;
  float v = lk[row * 64 + lane];
  float ss = v * v;
  for (int off = 32; off; off >>= 1) ss += __shfl_xor(ss, off, 64);
  float denom = sqrtf(ss) + EPS_F;
  float r = (act[row] > 0) ? (v / denom) : 0.0f;
  lkn[row * 64 + lane] = r;
  lknb[row * 64 + lane] = f2bf(r);
}

// ---------- project selected stm_K; fp32 Kproj + fp32/bf16 normalized ----------
__global__ void k_proj(const float* __restrict__ stmK, const float* __restrict__ W,
                       const float* __restrict__ bp, const int* __restrict__ sel,
                       float* __restrict__ Kproj, float* __restrict__ kpn,
                       unsigned short* __restrict__ kpnb) {
  int m = blockIdx.x;
  int j = threadIdx.x;            // 64 threads
  int s = sel[m];
  float acc = bp[j];
#pragma unroll
  for (int k = 0; k < 16; ++k) acc += stmK[s * 16 + k] * W[k * 64 + j];
  float ss = acc * acc;
  for (int off = 32; off; off >>= 1) ss += __shfl_xor(ss, off, 64);
  float denom = sqrtf(ss) + EPS_F;
  float r = acc / denom;
  Kproj[m * 64 + j] = acc;
  kpn[m * 64 + j] = r;
  kpnb[m * 64 + j] = f2bf(r);
}

// ---------- sweep 1: LDS-staged bf16 MFMA, per-(m,128-col split) max ----------
// grid (512 nsplits, 8 mblocks); block 512 thr = 8 waves; m-tile 256, n-tile 128
__global__ __launch_bounds__(512) void k_simmax(const unsigned short* __restrict__ kpnb,
                                                const unsigned short* __restrict__ lknb,
                                                float* __restrict__ partials) {
  // LDS layout: fragment order — 16B slot S = (t*2+kh)*64 + lane
  __shared__ char lds[16384];
  int tid = threadIdx.x;
  int lane = tid & 63, w = tid >> 6;
  int lg = lane >> 4, lc = lane & 15;
  int nbase = blockIdx.x * 128;
  int mbase = blockIdx.y * 256;

  // stage B-tile (128 rows x 128B = 16KB), 2 rounds of global_load_lds w=16.
  // Global source address carries the fragment permutation; LDS dest is linear.
#pragma unroll
  for (int r = 0; r < 2; ++r) {
    int slot = r * 512 + tid;            // slot & 63 == lane
    int kh = (slot >> 6) & 1;
    int t  = slot >> 7;
    const unsigned short* src = lknb + (size_t)(nbase + t * 16 + lc) * 64 + kh * 32 + lg * 8;
    char* dst = &lds[(size_t)(r * 512 + w * 64) * 16];   // wave-uniform base
    __builtin_amdgcn_global_load_lds((const __attribute__((address_space(1))) void*)src,
                                     (__attribute__((address_space(3))) void*)dst, 16, 0, 0);
  }

  // A fragments: 2 row-groups x 2 k-halves (rows mbase + w*32 + g*16 + lc)
  bf16x8 a[2][2];
#pragma unroll
  for (int g = 0; g < 2; ++g)
#pragma unroll
    for (int kh = 0; kh < 2; ++kh)
      a[g][kh] = *reinterpret_cast<const bf16x8*>(
          kpnb + (size_t)(mbase + w * 32 + g * 16 + lc) * 64 + kh * 32 + lg * 8);

  float bmax[2][4];
#pragma unroll
  for (int g = 0; g < 2; ++g)
#pragma unroll
    for (int r = 0; r < 4; ++r) bmax[g][r] = -FLT_MAX;

  __syncthreads();   // drains vmcnt for global_load_lds

#pragma unroll
  for (int t = 0; t < 8; ++t) {
    bf16x8 b0 = *reinterpret_cast<const bf16x8*>(&lds[(size_t)((t * 2 + 0) * 64 + lane) * 16]);
    bf16x8 b1 = *reinterpret_cast<const bf16x8*>(&lds[(size_t)((t * 2 + 1) * 64 + lane) * 16]);
#pragma unroll
    for (int g = 0; g < 2; ++g) {
      f32x4 z = {0.f, 0.f, 0.f, 0.f};
      f32x4 c = __builtin_amdgcn_mfma_f32_16x16x32_bf16(a[g][0], b0, z, 0, 0, 0);
      c = __builtin_amdgcn_mfma_f32_16x16x32_bf16(a[g][1], b1, c, 0, 0, 0);
#pragma unroll
      for (int r = 0; r < 4; ++r) bmax[g][r] = fmaxf(bmax[g][r], c[r]);
    }
  }

  // reduce over lc (cols); rows live at lane lg, reg r
#pragma unroll
  for (int g = 0; g < 2; ++g)
#pragma unroll
    for (int r = 0; r < 4; ++r) {
      float v = bmax[g][r];
#pragma unroll
      for (int mk = 1; mk <= 8; mk <<= 1) v = fmaxf(v, __shfl_xor(v, mk, 64));
      bmax[g][r] = v;
    }
  if (lc == 0) {
#pragma unroll
    for (int g = 0; g < 2; ++g)
#pragma unroll
      for (int r = 0; r < 4; ++r)
        partials[(size_t)(mbase + w * 32 + g * 16 + lg * 4 + r) * NSPL + blockIdx.x] = bmax[g][r];
  }
}

// ---------- per-row max over 512 splits; emit candidate-split worklist ----------
__global__ __launch_bounds__(128) void k_redmax(const float* __restrict__ partials,
                                                int* __restrict__ worklist,
                                                int* __restrict__ wcnt) {
  int m = blockIdx.x;
  int tid = threadIdx.x;
  f32x4 v = ((const f32x4*)(partials + (size_t)m * NSPL))[tid];
  float mx = fmaxf(fmaxf(v[0], v[1]), fmaxf(v[2], v[3]));
  for (int mk = 1; mk <= 32; mk <<= 1) mx = fmaxf(mx, __shfl_xor(mx, mk, 64));
  __shared__ float s[2];
  if ((tid & 63) == 0) s[tid >> 6] = mx;
  __syncthreads();
  float thr = fmaxf(s[0], s[1]) - MARGIN;
#pragma unroll
  for (int q = 0; q < 4; ++q) {
    if (v[q] >= thr) {
      int pos = atomicAdd(wcnt, 1);
      if (pos < WCAP) worklist[pos] = m * NSPL + tid * 4 + q;
    }
  }
}

// ---------- exact fp32 dots for candidate splits; atomicMax exact keys ----------
__global__ __launch_bounds__(64) void k_exact(const int* __restrict__ worklist,
                                              const int* __restrict__ wcnt,
                                              const float* __restrict__ kpn,
                                              const float* __restrict__ lkn,
                                              unsigned long long* __restrict__ finalkey) {
  int b = blockIdx.x;
  int cnt = *wcnt; if (cnt > WCAP) cnt = WCAP;
  if (b >= cnt) return;
  int e = worklist[b];
  int m = e >> 9, sp = e & (NSPL - 1);
  int lane = threadIdx.x;
  const float* ka = kpn + (size_t)m * 64;
  unsigned long long key = 0;
#pragma unroll
  for (int c = 0; c < 2; ++c) {
    int col = sp * 128 + c * 64 + lane;
    const float* kb = lkn + (size_t)col * 64;
    float ex = 0.f;
    for (int k = 0; k < 64; ++k) ex += ka[k] * kb[k];   // same order as R2 (passed)
    unsigned long long kk = ((unsigned long long)f2ord(ex) << 32) |
                            (unsigned long long)(0xFFFFFFFFu - (unsigned)col);
    if (kk > key) key = kk;
  }
  for (int mk = 1; mk <= 32; mk <<= 1) {
    unsigned long long o = shflxor64(key, mk);
    if (o > key) key = o;
  }
  if (lane == 0) atomicMax(finalkey + m, key);
}

// ---------- finalize + rank (one block) ----------
__global__ void k_rank(const unsigned long long* __restrict__ finalkey,
                       int* __restrict__ best, int* __restrict__ matched,
                       int* __restrict__ rank,
                       const float* __restrict__ fatigue, float* __restrict__ outF) {
  __shared__ int s[256];
  int tid = threadIdx.x;
  int base = tid * 8;
  int flags[8]; int c = 0;
#pragma unroll
  for (int q = 0; q < 8; ++q) {
    unsigned long long k = finalkey[base + q];
    float v = ord2f((unsigned int)(k >> 32));
    int mt = (v >= THRESH) ? 1 : 0;
    matched[base + q] = mt;
    best[base + q] = (int)(0xFFFFFFFFu - (unsigned int)(k & 0xFFFFFFFFull));
    flags[q] = mt ? 0 : 1;
    c += flags[q];
  }
  s[tid] = c;
  __syncthreads();
  for (int off = 1; off < 256; off <<= 1) {
    int v = (tid >= off) ? s[tid - off] : 0;
    __syncthreads();
    s[tid] += v;
    __syncthreads();
  }
  int run = s[tid] - c;
#pragma unroll
  for (int q = 0; q < 8; ++q) {
    rank[base + q] = flags[q] ? run : -1;
    run += flags[q];
  }
  if (tid == 0) outF[0] = 0.2f * fatigue[0];
}

// ---------- inactive slot compaction ----------
__global__ void k_cnt(const int* __restrict__ act, int* __restrict__ counts) {
  int i = blockIdx.x * 256 + threadIdx.x;
  int v = (act[i] == 0) ? 1 : 0;
  unsigned long long ball = __ballot(v);
  if ((threadIdx.x & 63) == 0) atomicAdd(&counts[blockIdx.x], __popcll(ball));
}

__global__ void k_scan256(const int* __restrict__ in, int* __restrict__ out) {
  __shared__ int s[256];
  int tid = threadIdx.x;
  int x = in[tid];
  s[tid] = x;
  __syncthreads();
  for (int off = 1; off < 256; off <<= 1) {
    int v = (tid >= off) ? s[tid - off] : 0;
    __syncthreads();
    s[tid] += v;
    __syncthreads();
  }
  out[tid] = s[tid] - x;
}

__global__ void k_compact(const int* __restrict__ act, const int* __restrict__ offsets,
                          int* __restrict__ inact) {
  __shared__ int s[256];
  int tid = threadIdx.x;
  int i = blockIdx.x * 256 + tid;
  int v = (act[i] == 0) ? 1 : 0;
  s[tid] = v;
  __syncthreads();
  for (int off = 1; off < 256; off <<= 1) {
    int u = (tid >= off) ? s[tid - off] : 0;
    __syncthreads();
    s[tid] += u;
    __syncthreads();
  }
  if (v) inact[offsets[blockIdx.x] + s[tid] - v] = i;
}

// ---------- scatter writes into ltm outputs ----------
__global__ void k_scatter(const int* __restrict__ matched, const int* __restrict__ best,
                          const int* __restrict__ rank, const int* __restrict__ sel,
                          const float* __restrict__ omega, const float* __restrict__ Kproj,
                          const float* __restrict__ stmV, const float* __restrict__ stmE,
                          const int* __restrict__ inact,
                          float* __restrict__ outK, float* __restrict__ outV,
                          float* __restrict__ outE, float* __restrict__ outH) {
  int m = blockIdx.x;
  int t = threadIdx.x;   // 128
  int s = sel[m];
  float om = omega[m];
  if (matched[m]) {
    int b = best[m];
    if (t < 64) atomicAdd(&outK[b * 64 + t], om * Kproj[m * 64 + t]);
    atomicAdd(&outV[b * 128 + t], om * stmV[s * 128 + t]);
    if (t < 4) atomicAdd(&outE[b * 4 + t], om * stmE[s * 4 + t]);
    if (t == 0) atomicAdd(&outH[b], om);
  } else {
    int slot = inact[rank[m]];
    if (t < 64) outK[slot * 64 + t] = Kproj[m * 64 + t];
    outV[slot * 128 + t] = stmV[s * 128 + t];
    if (t < 4) outE[slot * 4 + t] = stmE[s * 4 + t];
    if (t == 0) outH[slot] = om;
  }
}

// ---------- stm_V row-norm clip ----------
__global__ void k_vnorm(const float* __restrict__ V, float* __restrict__ out) {
  int tid = threadIdx.x;
  int row = blockIdx.x * 4 + (tid >> 6);
  int lane = tid & 63;
  float a = V[row * 128 + lane];
  float b = V[row * 128 + 64 + lane];
  float ss = a * a + b * b;
  for (int off = 32; off; off >>= 1) ss += __shfl_xor(ss, off, 64);
  float scale = fminf(1.0f, 2.0f / (sqrtf(ss) + EPS_F));
  out[row * 128 + lane] = a * scale;
  out[row * 128 + 64 + lane] = b * scale;
}

// ---------- terrain blur (13-tap separable, zero pad) ----------
struct GW13 { float w[13]; };

__global__ void k_blurW(const float* __restrict__ in, float* __restrict__ out, GW13 g) {
  int idx = blockIdx.x * 256 + threadIdx.x;
  int w = idx % 96;
  float s = 0.f;
#pragma unroll
  for (int t = -6; t <= 6; ++t) {
    int ww = w + t;
    if (ww >= 0 && ww < 96) s += g.w[t + 6] * in[idx + t];
  }
  out[idx] = s;
}

__global__ void k_blurH(const float* __restrict__ in, float* __restrict__ out, GW13 g) {
  int idx = blockIdx.x * 256 + threadIdx.x;
  int h = (idx / 96) % 96;
  float s = 0.f;
#pragma unroll
  for (int t = -6; t <= 6; ++t) {
    int hh = h + t;
    if (hh >= 0 && hh < 96) s += g.w[t + 6] * in[idx + t * 96];
  }
  out[idx] = s;
}

__global__ void k_blurD(const float* __restrict__ in, const float* __restrict__ ltmT,
                        float* __restrict__ out, GW13 g) {
  int idx = blockIdx.x * 256 + threadIdx.x;
  int d = (idx / 9216) % 96;
  int c = idx / 884736;
  float s = 0.f;
#pragma unroll
  for (int t = -6; t <= 6; ++t) {
    int dd = d + t;
    if (dd >= 0 && dd < 96) s += g.w[t + 6] * in[idx + t * 9216];
  }
  float xi = (c == 0) ? 0.005f : 0.003f;
  out[idx] = ltmT[idx] + xi * s;
}

// ---------- launch ----------
extern "C" void kernel_launch(void* const* d_in, const int* in_sizes, int n_in,
                              void* d_out, int out_size, void* d_ws, size_t ws_size,
                              hipStream_t stream) {
  const float* stmK = (const float*)d_in[0];
  const float* stmV = (const float*)d_in[1];
  const float* stmE = (const float*)d_in[2];
  const float* stmH = (const float*)d_in[3];
  const float* ltmK = (const float*)d_in[4];
  const float* ltmV = (const float*)d_in[5];
  const float* ltmE = (const float*)d_in[6];
  const float* ltmH = (const float*)d_in[7];
  const float* Wp   = (const float*)d_in[8];
  const float* bp   = (const float*)d_in[9];
  const float* sT   = (const float*)d_in[10];
  const float* lT   = (const float*)d_in[11];
  const float* fat  = (const float*)d_in[12];
  const int*   sAct = (const int*)d_in[13];
  const int*   lAct = (const int*)d_in[14];

  float* out = (float*)d_out;
  float* outK  = out;
  float* outV  = out + 4194304;
  float* outE  = out + 12582912;
  float* outH  = out + 12845056;
  float* outSV = out + 12910592;
  float* outT  = out + 21299200;
  float* outF  = out + 25722880;

  char* p = (char*)d_ws;
  auto alloc = [&](size_t bytes) -> void* {
    void* r = (void*)p;
    p += (bytes + 255) & ~(size_t)255;
    return r;
  };
  float* lkn      = (float*)alloc((size_t)N_LTM * 64 * 4);
  unsigned short* lknb = (unsigned short*)alloc((size_t)N_LTM * 64 * 2);
  float* kpn      = (float*)alloc((size_t)TOPM * 64 * 4);
  unsigned short* kpnb = (unsigned short*)alloc((size_t)TOPM * 64 * 2);
  float* Kproj    = (float*)alloc((size_t)TOPM * 64 * 4);
  unsigned long long* finalkey = (unsigned long long*)alloc(TOPM * 8);
  int*   wcnt     = (int*)alloc(256);
  int*   best     = (int*)alloc(TOPM * 4);
  int*   matched  = (int*)alloc(TOPM * 4);
  int*   rank     = (int*)alloc(TOPM * 4);
  int*   sel      = (int*)alloc(TOPM * 4);
  float* omega    = (float*)alloc(TOPM * 4);
  int*   hist     = (int*)alloc(NBINS * 4);
  int*   candcnt  = (int*)alloc(256);
  unsigned long long* cand = (unsigned long long*)alloc(CAND_CAP * 8);
  int*   thrbin   = (int*)alloc(256);
  int*   counts   = (int*)alloc(256 * 4);
  int*   offsets  = (int*)alloc(256 * 4);
  int*   inact    = (int*)alloc((size_t)N_LTM * 4);
  float* tmpA     = (float*)alloc((size_t)4423680 * 4);
  float* tmpB     = (float*)alloc((size_t)4423680 * 4);
  // aliases with disjoint stream-ordered lifetimes:
  //   partials (2048*512*4B = 4MB) on tmpA — consumed by k_redmax before k_blurW
  //   worklist (8192*4B) on tmpB        — consumed by k_exact before k_blurH
  float* partials = tmpA;
  int* worklist = (int*)tmpB;
  (void)ws_size; (void)in_sizes; (void)n_in; (void)out_size;

  hipMemcpyAsync(outK, ltmK, (size_t)4194304 * 4, hipMemcpyDeviceToDevice, stream);
  hipMemcpyAsync(outV, ltmV, (size_t)8388608 * 4, hipMemcpyDeviceToDevice, stream);
  hipMemcpyAsync(outE, ltmE, (size_t)262144 * 4, hipMemcpyDeviceToDevice, stream);
  hipMemcpyAsync(outH, ltmH, (size_t)65536 * 4, hipMemcpyDeviceToDevice, stream);

  k_zero<<<16, 256, 0, stream>>>(hist, counts, candcnt, wcnt, finalkey);

  // top-M selection
  k_hist<<<256, 256, 0, stream>>>(stmH, sAct, hist);
  k_thresh<<<1, 1024, 0, stream>>>(hist, thrbin);
  k_gather<<<256, 256, 0, stream>>>(stmH, sAct, thrbin, cand, candcnt);
  k_sortsel<<<1, 1024, 0, stream>>>(stmH, cand, candcnt, sel, omega);

  // normalize + project (fp32 + bf16 copies)
  k_lknorm<<<N_LTM / 4, 256, 0, stream>>>(ltmK, lAct, lkn, lknb);
  k_proj<<<TOPM, 64, 0, stream>>>(stmK, Wp, bp, sel, Kproj, kpn, kpnb);

  // MFMA split-max sweep -> candidate splits -> exact fp32 rescue
  k_simmax<<<dim3(NSPL, 8), 512, 0, stream>>>(kpnb, lknb, partials);
  k_redmax<<<TOPM, 128, 0, stream>>>(partials, worklist, wcnt);
  k_exact<<<WCAP, 64, 0, stream>>>(worklist, wcnt, kpn, lkn, finalkey);

  // finalize + ranks + inactive slot list
  k_rank<<<1, 256, 0, stream>>>(finalkey, best, matched, rank, fat, outF);
  k_cnt<<<256, 256, 0, stream>>>(lAct, counts);
  k_scan256<<<1, 256, 0, stream>>>(counts, offsets);
  k_compact<<<256, 256, 0, stream>>>(lAct, offsets, inact);

  // scatter into ltm outputs
  k_scatter<<<TOPM, 128, 0, stream>>>(matched, best, rank, sel, omega, Kproj,
                                      stmV, stmE, inact, outK, outV, outE, outH);

  // stm_V normalization
  k_vnorm<<<N_STM / 4, 256, 0, stream>>>(stmV, outSV);

  // terrain blur
  GW13 g;
  {
    float s = 0.f;
    for (int i = -6; i <= 6; ++i) {
      float v = expf(-0.5f * ((float)i / 2.0f) * ((float)i / 2.0f));
      g.w[i + 6] = v;
      s += v;
    }
    for (int i = 0; i < 13; ++i) g.w[i] /= s;
  }
  int tblocks = 4423680 / 256;
  k_blurW<<<tblocks, 256, 0, stream>>>(sT, tmpA, g);
  k_blurH<<<tblocks, 256, 0, stream>>>(tmpA, tmpB, g);
  k_blurD<<<tblocks, 256, 0, stream>>>(tmpB, lT, outT, g);
}

// Round 4
// 509.171 us; speedup vs baseline: 1.4886x; 1.0655x over previous
//
#include <hip/hip_runtime.h>
#include <hip/hip_bf16.h>
#include <cfloat>
#include <cstdint>

#define N_STM 65536
#define N_LTM 65536
#define TOPM 2048
#define NBINS 4096
#define CAND_CAP 4096
#define NSPL 512          // 128-col splits of N_LTM
#define WCAP 8192         // worklist capacity (expected ~3K entries)
#define KAPPA 0.05f
#define EPS_F 1e-8f
#define THRESH 0.5f
#define MARGIN 0.01f      // > 2 * bf16 sim error (7.8e-3)

typedef __attribute__((ext_vector_type(8))) __bf16 bf16x8;
typedef __attribute__((ext_vector_type(4))) float f32x4;

// ---------- helpers ----------
__device__ __forceinline__ unsigned int f2ord(float f) {
  unsigned int b = __float_as_uint(f);
  return b ^ ((b & 0x80000000u) ? 0xFFFFFFFFu : 0x80000000u);
}
__device__ __forceinline__ float ord2f(unsigned int u) {
  unsigned int b = (u & 0x80000000u) ? (u ^ 0x80000000u) : ~u;
  return __uint_as_float(b);
}
__device__ __forceinline__ unsigned short f2bf(float f) {
  __hip_bfloat16 h = __float2bfloat16(f);
  return __builtin_bit_cast(unsigned short, h);
}
__device__ __forceinline__ unsigned long long shflxor64(unsigned long long v, int mask) {
  unsigned int lo = (unsigned int)v, hi = (unsigned int)(v >> 32);
  lo = __shfl_xor(lo, mask, 64);
  hi = __shfl_xor(hi, mask, 64);
  return ((unsigned long long)hi << 32) | lo;
}

// ---------- one-shot zero init (replaces 4 memsets) ----------
__global__ void k_zero(int* __restrict__ hist, int* __restrict__ counts,
                       int* __restrict__ candcnt, int* __restrict__ wcnt,
                       unsigned long long* __restrict__ finalkey) {
  int i = blockIdx.x * 256 + threadIdx.x;   // grid 16 -> 4096 threads
  hist[i] = 0;
  if (i < 2048) finalkey[i] = 0ull;
  if (i < 256) counts[i] = 0;
  if (i == 0) { candcnt[0] = 0; wcnt[0] = 0; }
}

// ---------- top-k: histogram ----------
__global__ void k_hist(const float* __restrict__ h, const int* __restrict__ act,
                       int* __restrict__ hist) {
  int i = blockIdx.x * blockDim.x + threadIdx.x;
  if (i >= N_STM) return;
  if (act[i] > 0) {
    float v = h[i];
    int b = (int)(v * (float)NBINS);
    b = min(max(b, 0), NBINS - 1);
    atomicAdd(&hist[b], 1);
  }
}

__global__ __launch_bounds__(1024) void k_thresh(const int* __restrict__ hist,
                                                 int* __restrict__ thrbin) {
  __shared__ int t[1024];
  int tid = threadIdx.x;
  int c0 = hist[tid * 4 + 0], c1 = hist[tid * 4 + 1];
  int c2 = hist[tid * 4 + 2], c3 = hist[tid * 4 + 3];
  int local = c0 + c1 + c2 + c3;
  t[tid] = local;
  __syncthreads();
  for (int off = 1; off < 1024; off <<= 1) {
    int v = (tid + off < 1024) ? t[tid + off] : 0;
    __syncthreads();
    t[tid] += v;
    __syncthreads();
  }
  int after = t[tid] - local;
  int s3 = c3, s2 = c2 + s3, s1 = c1 + s2, s0 = c0 + s1;
  int S0 = after + s0, S1 = after + s1, S2 = after + s2, S3 = after + s3, S4 = after;
  if (S0 >= TOPM && S1 < TOPM) *thrbin = tid * 4 + 0;
  if (S1 >= TOPM && S2 < TOPM) *thrbin = tid * 4 + 1;
  if (S2 >= TOPM && S3 < TOPM) *thrbin = tid * 4 + 2;
  if (S3 >= TOPM && S4 < TOPM) *thrbin = tid * 4 + 3;
}

__global__ void k_gather(const float* __restrict__ h, const int* __restrict__ act,
                         const int* __restrict__ thrbin,
                         unsigned long long* __restrict__ cand, int* __restrict__ cnt) {
  int i = blockIdx.x * blockDim.x + threadIdx.x;
  if (i >= N_STM) return;
  if (act[i] > 0) {
    float v = h[i];
    int b = (int)(v * (float)NBINS);
    b = min(max(b, 0), NBINS - 1);
    if (b >= *thrbin) {
      int pos = atomicAdd(cnt, 1);
      if (pos < CAND_CAP)
        cand[pos] = ((unsigned long long)f2ord(v) << 32) |
                    (unsigned long long)(0xFFFFFFFFu - (unsigned)i);
    }
  }
}

// ---------- rank-select: replaces single-block bitonic sort ----------
// rank = #{keys > mine} (keys strictly ordered via embedded ~idx);
// rank < TOPM  =>  sel[rank] = idx. Same output as descending stable sort.
__global__ __launch_bounds__(256) void k_ranksel(const float* __restrict__ h,
                                                 const unsigned long long* __restrict__ cand,
                                                 const int* __restrict__ cnt,
                                                 int* __restrict__ sel,
                                                 float* __restrict__ omega) {
  __shared__ unsigned long long keys[1024];
  int C = *cnt; if (C > CAND_CAP) C = CAND_CAP;
  int t = blockIdx.x * 256 + threadIdx.x;
  unsigned long long mine = (t < C) ? cand[t] : 0ull;
  int r = 0;
  for (int base = 0; base < C; base += 1024) {
    int lim = min(1024, C - base);
    __syncthreads();
    for (int j = threadIdx.x; j < lim; j += 256) keys[j] = cand[base + j];
    __syncthreads();
    for (int j = 0; j < lim; ++j) r += (keys[j] > mine) ? 1 : 0;   // LDS broadcast
  }
  if (t < C && r < TOPM) {
    int idx = (int)(0xFFFFFFFFu - (unsigned int)(mine & 0xFFFFFFFFull));
    sel[r] = idx;
    omega[r] = KAPPA * h[idx];
  }
}

// ---------- normalize ltm_K rows (inactive -> zero); fp32 + bf16 ----------
__global__ void k_lknorm(const float* __restrict__ lk, const int* __restrict__ act,
                         float* __restrict__ lkn, unsigned short* __restrict__ lknb) {
  int tid = threadIdx.x;
  int row = blockIdx.x * 4 + (tid >> 6);
  int lane = tid & 63;
  float v = lk[row * 64 + lane];
  float ss = v * v;
  for (int off = 32; off; off >>= 1) ss += __shfl_xor(ss, off, 64);
  float denom = sqrtf(ss) + EPS_F;
  float r = (act[row] > 0) ? (v / denom) : 0.0f;
  lkn[row * 64 + lane] = r;
  lknb[row * 64 + lane] = f2bf(r);
}

// ---------- project selected stm_K; fp32 Kproj + fp32/bf16 normalized ----------
__global__ void k_proj(const float* __restrict__ stmK, const float* __restrict__ W,
                       const float* __restrict__ bp, const int* __restrict__ sel,
                       float* __restrict__ Kproj, float* __restrict__ kpn,
                       unsigned short* __restrict__ kpnb) {
  int m = blockIdx.x;
  int j = threadIdx.x;            // 64 threads
  int s = sel[m];
  float acc = bp[j];
#pragma unroll
  for (int k = 0; k < 16; ++k) acc += stmK[s * 16 + k] * W[k * 64 + j];
  float ss = acc * acc;
  for (int off = 32; off; off >>= 1) ss += __shfl_xor(ss, off, 64);
  float denom = sqrtf(ss) + EPS_F;
  float r = acc / denom;
  Kproj[m * 64 + j] = acc;
  kpn[m * 64 + j] = r;
  kpnb[m * 64 + j] = f2bf(r);
}

// ---------- sweep 1: LDS-staged bf16 MFMA, per-(m,128-col split) max ----------
// grid (512 nsplits, 8 mblocks); block 512 thr = 8 waves; m-tile 256, n-tile 128
__global__ __launch_bounds__(512) void k_simmax(const unsigned short* __restrict__ kpnb,
                                                const unsigned short* __restrict__ lknb,
                                                float* __restrict__ partials) {
  // LDS layout: fragment order — 16B slot S = (t*2+kh)*64 + lane
  __shared__ char lds[16384];
  int tid = threadIdx.x;
  int lane = tid & 63, w = tid >> 6;
  int lg = lane >> 4, lc = lane & 15;
  int nbase = blockIdx.x * 128;
  int mbase = blockIdx.y * 256;

  // stage B-tile (128 rows x 128B = 16KB), 2 rounds of global_load_lds w=16.
  // Global source address carries the fragment permutation; LDS dest is linear.
#pragma unroll
  for (int r = 0; r < 2; ++r) {
    int slot = r * 512 + tid;            // slot & 63 == lane
    int kh = (slot >> 6) & 1;
    int t  = slot >> 7;
    const unsigned short* src = lknb + (size_t)(nbase + t * 16 + lc) * 64 + kh * 32 + lg * 8;
    char* dst = &lds[(size_t)(r * 512 + w * 64) * 16];   // wave-uniform base
    __builtin_amdgcn_global_load_lds((const __attribute__((address_space(1))) void*)src,
                                     (__attribute__((address_space(3))) void*)dst, 16, 0, 0);
  }

  // A fragments: 2 row-groups x 2 k-halves (rows mbase + w*32 + g*16 + lc)
  bf16x8 a[2][2];
#pragma unroll
  for (int g = 0; g < 2; ++g)
#pragma unroll
    for (int kh = 0; kh < 2; ++kh)
      a[g][kh] = *reinterpret_cast<const bf16x8*>(
          kpnb + (size_t)(mbase + w * 32 + g * 16 + lc) * 64 + kh * 32 + lg * 8);

  float bmax[2][4];
#pragma unroll
  for (int g = 0; g < 2; ++g)
#pragma unroll
    for (int r = 0; r < 4; ++r) bmax[g][r] = -FLT_MAX;

  __syncthreads();   // drains vmcnt for global_load_lds

#pragma unroll
  for (int t = 0; t < 8; ++t) {
    bf16x8 b0 = *reinterpret_cast<const bf16x8*>(&lds[(size_t)((t * 2 + 0) * 64 + lane) * 16]);
    bf16x8 b1 = *reinterpret_cast<const bf16x8*>(&lds[(size_t)((t * 2 + 1) * 64 + lane) * 16]);
#pragma unroll
    for (int g = 0; g < 2; ++g) {
      f32x4 z = {0.f, 0.f, 0.f, 0.f};
      f32x4 c = __builtin_amdgcn_mfma_f32_16x16x32_bf16(a[g][0], b0, z, 0, 0, 0);
      c = __builtin_amdgcn_mfma_f32_16x16x32_bf16(a[g][1], b1, c, 0, 0, 0);
#pragma unroll
      for (int r = 0; r < 4; ++r) bmax[g][r] = fmaxf(bmax[g][r], c[r]);
    }
  }

  // reduce over lc (cols); rows live at lane lg, reg r
#pragma unroll
  for (int g = 0; g < 2; ++g)
#pragma unroll
    for (int r = 0; r < 4; ++r) {
      float v = bmax[g][r];
#pragma unroll
      for (int mk = 1; mk <= 8; mk <<= 1) v = fmaxf(v, __shfl_xor(v, mk, 64));
      bmax[g][r] = v;
    }
  if (lc == 0) {
#pragma unroll
    for (int g = 0; g < 2; ++g)
#pragma unroll
      for (int r = 0; r < 4; ++r)
        partials[(size_t)(mbase + w * 32 + g * 16 + lg * 4 + r) * NSPL + blockIdx.x] = bmax[g][r];
  }
}

// ---------- per-row max over 512 splits; emit candidate-split worklist ----------
__global__ __launch_bounds__(128) void k_redmax(const float* __restrict__ partials,
                                                int* __restrict__ worklist,
                                                int* __restrict__ wcnt) {
  int m = blockIdx.x;
  int tid = threadIdx.x;
  f32x4 v = ((const f32x4*)(partials + (size_t)m * NSPL))[tid];
  float mx = fmaxf(fmaxf(v[0], v[1]), fmaxf(v[2], v[3]));
  for (int mk = 1; mk <= 32; mk <<= 1) mx = fmaxf(mx, __shfl_xor(mx, mk, 64));
  __shared__ float s[2];
  if ((tid & 63) == 0) s[tid >> 6] = mx;
  __syncthreads();
  float thr = fmaxf(s[0], s[1]) - MARGIN;
#pragma unroll
  for (int q = 0; q < 4; ++q) {
    if (v[q] >= thr) {
      int pos = atomicAdd(wcnt, 1);
      if (pos < WCAP) worklist[pos] = m * NSPL + tid * 4 + q;
    }
  }
}

// ---------- exact fp32 dots for candidate splits; atomicMax exact keys ----------
__global__ __launch_bounds__(64) void k_exact(const int* __restrict__ worklist,
                                              const int* __restrict__ wcnt,
                                              const float* __restrict__ kpn,
                                              const float* __restrict__ lkn,
                                              unsigned long long* __restrict__ finalkey) {
  int b = blockIdx.x;
  int cnt = *wcnt; if (cnt > WCAP) cnt = WCAP;
  if (b >= cnt) return;
  int e = worklist[b];
  int m = e >> 9, sp = e & (NSPL - 1);
  int lane = threadIdx.x;
  const float* ka = kpn + (size_t)m * 64;
  unsigned long long key = 0;
#pragma unroll
  for (int c = 0; c < 2; ++c) {
    int col = sp * 128 + c * 64 + lane;
    const float* kb = lkn + (size_t)col * 64;
    float ex = 0.f;
    for (int k = 0; k < 64; ++k) ex += ka[k] * kb[k];   // same order as R2 (passed)
    unsigned long long kk = ((unsigned long long)f2ord(ex) << 32) |
                            (unsigned long long)(0xFFFFFFFFu - (unsigned)col);
    if (kk > key) key = kk;
  }
  for (int mk = 1; mk <= 32; mk <<= 1) {
    unsigned long long o = shflxor64(key, mk);
    if (o > key) key = o;
  }
  if (lane == 0) atomicMax(finalkey + m, key);
}

// ---------- finalize + rank (one block) ----------
__global__ void k_rank(const unsigned long long* __restrict__ finalkey,
                       int* __restrict__ best, int* __restrict__ matched,
                       int* __restrict__ rank,
                       const float* __restrict__ fatigue, float* __restrict__ outF) {
  __shared__ int s[256];
  int tid = threadIdx.x;
  int base = tid * 8;
  int flags[8]; int c = 0;
#pragma unroll
  for (int q = 0; q < 8; ++q) {
    unsigned long long k = finalkey[base + q];
    float v = ord2f((unsigned int)(k >> 32));
    int mt = (v >= THRESH) ? 1 : 0;
    matched[base + q] = mt;
    best[base + q] = (int)(0xFFFFFFFFu - (unsigned int)(k & 0xFFFFFFFFull));
    flags[q] = mt ? 0 : 1;
    c += flags[q];
  }
  s[tid] = c;
  __syncthreads();
  for (int off = 1; off < 256; off <<= 1) {
    int v = (tid >= off) ? s[tid - off] : 0;
    __syncthreads();
    s[tid] += v;
    __syncthreads();
  }
  int run = s[tid] - c;
#pragma unroll
  for (int q = 0; q < 8; ++q) {
    rank[base + q] = flags[q] ? run : -1;
    run += flags[q];
  }
  if (tid == 0) outF[0] = 0.2f * fatigue[0];
}

// ---------- inactive slot compaction ----------
__global__ void k_cnt(const int* __restrict__ act, int* __restrict__ counts) {
  int i = blockIdx.x * 256 + threadIdx.x;
  int v = (act[i] == 0) ? 1 : 0;
  unsigned long long ball = __ballot(v);
  if ((threadIdx.x & 63) == 0) atomicAdd(&counts[blockIdx.x], __popcll(ball));
}

__global__ void k_scan256(const int* __restrict__ in, int* __restrict__ out) {
  __shared__ int s[256];
  int tid = threadIdx.x;
  int x = in[tid];
  s[tid] = x;
  __syncthreads();
  for (int off = 1; off < 256; off <<= 1) {
    int v = (tid >= off) ? s[tid - off] : 0;
    __syncthreads();
    s[tid] += v;
    __syncthreads();
  }
  out[tid] = s[tid] - x;
}

__global__ void k_compact(const int* __restrict__ act, const int* __restrict__ offsets,
                          int* __restrict__ inact) {
  __shared__ int s[256];
  int tid = threadIdx.x;
  int i = blockIdx.x * 256 + tid;
  int v = (act[i] == 0) ? 1 : 0;
  s[tid] = v;
  __syncthreads();
  for (int off = 1; off < 256; off <<= 1) {
    int u = (tid >= off) ? s[tid - off] : 0;
    __syncthreads();
    s[tid] += u;
    __syncthreads();
  }
  if (v) inact[offsets[blockIdx.x] + s[tid] - v] = i;
}

// ---------- scatter writes into ltm outputs ----------
__global__ void k_scatter(const int* __restrict__ matched, const int* __restrict__ best,
                          const int* __restrict__ rank, const int* __restrict__ sel,
                          const float* __restrict__ omega, const float* __restrict__ Kproj,
                          const float* __restrict__ stmV, const float* __restrict__ stmE,
                          const int* __restrict__ inact,
                          float* __restrict__ outK, float* __restrict__ outV,
                          float* __restrict__ outE, float* __restrict__ outH) {
  int m = blockIdx.x;
  int t = threadIdx.x;   // 128
  int s = sel[m];
  float om = omega[m];
  if (matched[m]) {
    int b = best[m];
    if (t < 64) atomicAdd(&outK[b * 64 + t], om * Kproj[m * 64 + t]);
    atomicAdd(&outV[b * 128 + t], om * stmV[s * 128 + t]);
    if (t < 4) atomicAdd(&outE[b * 4 + t], om * stmE[s * 4 + t]);
    if (t == 0) atomicAdd(&outH[b], om);
  } else {
    int slot = inact[rank[m]];
    if (t < 64) outK[slot * 64 + t] = Kproj[m * 64 + t];
    outV[slot * 128 + t] = stmV[s * 128 + t];
    if (t < 4) outE[slot * 4 + t] = stmE[s * 4 + t];
    if (t == 0) outH[slot] = om;
  }
}

// ---------- stm_V row-norm clip ----------
__global__ void k_vnorm(const float* __restrict__ V, float* __restrict__ out) {
  int tid = threadIdx.x;
  int row = blockIdx.x * 4 + (tid >> 6);
  int lane = tid & 63;
  float a = V[row * 128 + lane];
  float b = V[row * 128 + 64 + lane];
  float ss = a * a + b * b;
  for (int off = 32; off; off >>= 1) ss += __shfl_xor(ss, off, 64);
  float scale = fminf(1.0f, 2.0f / (sqrtf(ss) + EPS_F));
  out[row * 128 + lane] = a * scale;
  out[row * 128 + 64 + lane] = b * scale;
}

// ---------- terrain blur (13-tap separable, zero pad) ----------
struct GW13 { float w[13]; };

__global__ void k_blurW(const float* __restrict__ in, float* __restrict__ out, GW13 g) {
  int idx = blockIdx.x * 256 + threadIdx.x;
  int w = idx % 96;
  float s = 0.f;
#pragma unroll
  for (int t = -6; t <= 6; ++t) {
    int ww = w + t;
    if (ww >= 0 && ww < 96) s += g.w[t + 6] * in[idx + t];
  }
  out[idx] = s;
}

__global__ void k_blurH(const float* __restrict__ in, float* __restrict__ out, GW13 g) {
  int idx = blockIdx.x * 256 + threadIdx.x;
  int h = (idx / 96) % 96;
  float s = 0.f;
#pragma unroll
  for (int t = -6; t <= 6; ++t) {
    int hh = h + t;
    if (hh >= 0 && hh < 96) s += g.w[t + 6] * in[idx + t * 96];
  }
  out[idx] = s;
}

__global__ void k_blurD(const float* __restrict__ in, const float* __restrict__ ltmT,
                        float* __restrict__ out, GW13 g) {
  int idx = blockIdx.x * 256 + threadIdx.x;
  int d = (idx / 9216) % 96;
  int c = idx / 884736;
  float s = 0.f;
#pragma unroll
  for (int t = -6; t <= 6; ++t) {
    int dd = d + t;
    if (dd >= 0 && dd < 96) s += g.w[t + 6] * in[idx + t * 9216];
  }
  float xi = (c == 0) ? 0.005f : 0.003f;
  out[idx] = ltmT[idx] + xi * s;
}

// ---------- launch ----------
extern "C" void kernel_launch(void* const* d_in, const int* in_sizes, int n_in,
                              void* d_out, int out_size, void* d_ws, size_t ws_size,
                              hipStream_t stream) {
  const float* stmK = (const float*)d_in[0];
  const float* stmV = (const float*)d_in[1];
  const float* stmE = (const float*)d_in[2];
  const float* stmH = (const float*)d_in[3];
  const float* ltmK = (const float*)d_in[4];
  const float* ltmV = (const float*)d_in[5];
  const float* ltmE = (const float*)d_in[6];
  const float* ltmH = (const float*)d_in[7];
  const float* Wp   = (const float*)d_in[8];
  const float* bp   = (const float*)d_in[9];
  const float* sT   = (const float*)d_in[10];
  const float* lT   = (const float*)d_in[11];
  const float* fat  = (const float*)d_in[12];
  const int*   sAct = (const int*)d_in[13];
  const int*   lAct = (const int*)d_in[14];

  float* out = (float*)d_out;
  float* outK  = out;
  float* outV  = out + 4194304;
  float* outE  = out + 12582912;
  float* outH  = out + 12845056;
  float* outSV = out + 12910592;
  float* outT  = out + 21299200;
  float* outF  = out + 25722880;

  char* p = (char*)d_ws;
  auto alloc = [&](size_t bytes) -> void* {
    void* r = (void*)p;
    p += (bytes + 255) & ~(size_t)255;
    return r;
  };
  float* lkn      = (float*)alloc((size_t)N_LTM * 64 * 4);
  unsigned short* lknb = (unsigned short*)alloc((size_t)N_LTM * 64 * 2);
  float* kpn      = (float*)alloc((size_t)TOPM * 64 * 4);
  unsigned short* kpnb = (unsigned short*)alloc((size_t)TOPM * 64 * 2);
  float* Kproj    = (float*)alloc((size_t)TOPM * 64 * 4);
  unsigned long long* finalkey = (unsigned long long*)alloc(TOPM * 8);
  int*   wcnt     = (int*)alloc(256);
  int*   best     = (int*)alloc(TOPM * 4);
  int*   matched  = (int*)alloc(TOPM * 4);
  int*   rank     = (int*)alloc(TOPM * 4);
  int*   sel      = (int*)alloc(TOPM * 4);
  float* omega    = (float*)alloc(TOPM * 4);
  int*   hist     = (int*)alloc(NBINS * 4);
  int*   candcnt  = (int*)alloc(256);
  unsigned long long* cand = (unsigned long long*)alloc(CAND_CAP * 8);
  int*   thrbin   = (int*)alloc(256);
  int*   counts   = (int*)alloc(256 * 4);
  int*   offsets  = (int*)alloc(256 * 4);
  int*   inact    = (int*)alloc((size_t)N_LTM * 4);
  float* tmpA     = (float*)alloc((size_t)4423680 * 4);
  float* tmpB     = (float*)alloc((size_t)4423680 * 4);
  // aliases with disjoint stream-ordered lifetimes:
  //   partials (2048*512*4B = 4MB) on tmpA — consumed by k_redmax before k_blurW
  //   worklist (8192*4B) on tmpB        — consumed by k_exact before k_blurH
  float* partials = tmpA;
  int* worklist = (int*)tmpB;
  (void)ws_size; (void)in_sizes; (void)n_in; (void)out_size;

  hipMemcpyAsync(outK, ltmK, (size_t)4194304 * 4, hipMemcpyDeviceToDevice, stream);
  hipMemcpyAsync(outV, ltmV, (size_t)8388608 * 4, hipMemcpyDeviceToDevice, stream);
  hipMemcpyAsync(outE, ltmE, (size_t)262144 * 4, hipMemcpyDeviceToDevice, stream);
  hipMemcpyAsync(outH, ltmH, (size_t)65536 * 4, hipMemcpyDeviceToDevice, stream);

  k_zero<<<16, 256, 0, stream>>>(hist, counts, candcnt, wcnt, finalkey);

  // top-M selection
  k_hist<<<256, 256, 0, stream>>>(stmH, sAct, hist);
  k_thresh<<<1, 1024, 0, stream>>>(hist, thrbin);
  k_gather<<<256, 256, 0, stream>>>(stmH, sAct, thrbin, cand, candcnt);
  k_ranksel<<<16, 256, 0, stream>>>(stmH, cand, candcnt, sel, omega);

  // normalize + project (fp32 + bf16 copies)
  k_lknorm<<<N_LTM / 4, 256, 0, stream>>>(ltmK, lAct, lkn, lknb);
  k_proj<<<TOPM, 64, 0, stream>>>(stmK, Wp, bp, sel, Kproj, kpn, kpnb);

  // MFMA split-max sweep -> candidate splits -> exact fp32 rescue
  k_simmax<<<dim3(NSPL, 8), 512, 0, stream>>>(kpnb, lknb, partials);
  k_redmax<<<TOPM, 128, 0, stream>>>(partials, worklist, wcnt);
  k_exact<<<WCAP, 64, 0, stream>>>(worklist, wcnt, kpn, lkn, finalkey);

  // finalize + ranks + inactive slot list
  k_rank<<<1, 256, 0, stream>>>(finalkey, best, matched, rank, fat, outF);
  k_cnt<<<256, 256, 0, stream>>>(lAct, counts);
  k_scan256<<<1, 256, 0, stream>>>(counts, offsets);
  k_compact<<<256, 256, 0, stream>>>(lAct, offsets, inact);

  // scatter into ltm outputs
  k_scatter<<<TOPM, 128, 0, stream>>>(matched, best, rank, sel, omega, Kproj,
                                      stmV, stmE, inact, outK, outV, outE, outH);

  // stm_V normalization
  k_vnorm<<<N_STM / 4, 256, 0, stream>>>(stmV, outSV);

  // terrain blur
  GW13 g;
  {
    float s = 0.f;
    for (int i = -6; i <= 6; ++i) {
      float v = expf(-0.5f * ((float)i / 2.0f) * ((float)i / 2.0f));
      g.w[i + 6] = v;
      s += v;
    }
    for (int i = 0; i < 13; ++i) g.w[i] /= s;
  }
  int tblocks = 4423680 / 256;
  k_blurW<<<tblocks, 256, 0, stream>>>(sT, tmpA, g);
  k_blurH<<<tblocks, 256, 0, stream>>>(tmpA, tmpB, g);
  k_blurD<<<tblocks, 256, 0, stream>>>(tmpB, lT, outT, g);
}